// Round 3
// baseline (986.022 us; speedup 1.0000x reference)
//
#include <hip/hip_runtime.h>
#include <hip/hip_bf16.h>
#include <math.h>

// Problem constants
#define DIM   1024
#define NHEAD 16
#define SLEN  2048
#define BATCH 2
#define NROWS (BATCH*SLEN)   // 4096
#define QKV_N 3072

__device__ __forceinline__ float bfr(float x) {
  // float -> bf16 (RNE) -> float
  return __bfloat162float(__float2bfloat16(x));
}

// ---------------- rope tables (match numpy f32 semantics) ----------------
__global__ void __launch_bounds__(256) k_rope_tab(float* __restrict__ cosT,
                                                  float* __restrict__ sinT) {
  int idx = blockIdx.x * 256 + threadIdx.x;        // 2048*32 = 65536
  int s = idx >> 5, j = idx & 31;
  double inv  = 1.0 / pow(10000.0, (double)(2 * j) / 64.0);
  double ramp = ((double)(2 * j) / 64.0 - 0.25) / 0.75;
  ramp = ramp < 0.0 ? 0.0 : (ramp > 1.0 ? 1.0 : ramp);
  inv /= (ramp * 3.0 + 1.0);                       // yarn: 1/scale - 1 = 3
  float freq = (float)s * (float)inv;              // f32 product like reference
  cosT[idx] = (float)cos((double)freq);
  sinT[idx] = (float)sin((double)freq);
}

// ---------------- ternary quantization (bf16-faithful) ----------------
// one 64-lane wave per group of 64 consecutive elements
__global__ void __launch_bounds__(256) k_ternary(const float* __restrict__ in,
                                                 float* __restrict__ out) {
  int idx = blockIdx.x * 256 + threadIdx.x;
  float wb = bfr(in[idx]);
  float a = fabsf(wb);
  #pragma unroll
  for (int off = 32; off >= 1; off >>= 1) a += __shfl_xor(a, off);
  float scale = bfr(a * (1.0f / 64.0f));           // bf16 mean (f32 accum)
  scale = fmaxf(scale, 1e-8f);
  float ratio = bfr(wb / scale);
  float q = rintf(ratio);                          // half-to-even like jnp.round
  q = fminf(1.0f, fmaxf(-1.0f, q));
  float deq = bfr(q * scale);
  // forward value is bf16(wb + bf16(deq - wb))
  float d = bfr(deq - wb);
  out[idx] = bfr(wb + d);
}

// ---------------- fp32 GEMM  C[M,N] = A[M,K] * B[N,K]^T ----------------
// BM=BN=128, BK=16, 256 threads, 8x8 microtile
__global__ void __launch_bounds__(256) k_gemm_nt(const float* __restrict__ A,
                                                 const float* __restrict__ B,
                                                 float* __restrict__ C,
                                                 int M, int N, int K) {
  __shared__ float As[16][132];
  __shared__ float Bs[16][132];
  const int t = threadIdx.x;
  const int bm = blockIdx.y * 128, bn = blockIdx.x * 128;
  const int tx = t & 15, ty = t >> 4;
  float acc[8][8] = {};
  for (int k0 = 0; k0 < K; k0 += 16) {
    #pragma unroll
    for (int l = 0; l < 2; ++l) {
      int f = l * 1024 + t * 4;
      int r = f >> 4, c = f & 15;
      float4 va = *(const float4*)(A + (size_t)(bm + r) * K + k0 + c);
      As[c + 0][r] = va.x; As[c + 1][r] = va.y; As[c + 2][r] = va.z; As[c + 3][r] = va.w;
      float4 vb = *(const float4*)(B + (size_t)(bn + r) * K + k0 + c);
      Bs[c + 0][r] = vb.x; Bs[c + 1][r] = vb.y; Bs[c + 2][r] = vb.z; Bs[c + 3][r] = vb.w;
    }
    __syncthreads();
    #pragma unroll
    for (int kk = 0; kk < 16; ++kk) {
      float4 a0 = *(const float4*)&As[kk][ty * 8];
      float4 a1 = *(const float4*)&As[kk][ty * 8 + 4];
      float4 b0 = *(const float4*)&Bs[kk][tx * 8];
      float4 b1 = *(const float4*)&Bs[kk][tx * 8 + 4];
      float av[8] = {a0.x, a0.y, a0.z, a0.w, a1.x, a1.y, a1.z, a1.w};
      float bv[8] = {b0.x, b0.y, b0.z, b0.w, b1.x, b1.y, b1.z, b1.w};
      #pragma unroll
      for (int i = 0; i < 8; ++i)
        #pragma unroll
        for (int j = 0; j < 8; ++j)
          acc[i][j] = fmaf(av[i], bv[j], acc[i][j]);
    }
    __syncthreads();
  }
  #pragma unroll
  for (int i = 0; i < 8; ++i) {
    float4 o0 = {acc[i][0], acc[i][1], acc[i][2], acc[i][3]};
    float4 o1 = {acc[i][4], acc[i][5], acc[i][6], acc[i][7]};
    *(float4*)(C + (size_t)(bm + ty * 8 + i) * N + bn + tx * 8) = o0;
    *(float4*)(C + (size_t)(bm + ty * 8 + i) * N + bn + tx * 8 + 4) = o1;
  }
}

// ---------------- rmsnorm + rope + q_gain ----------------
// one wave per (row, {q-head or k-head}); lane = dim 0..63
__global__ void __launch_bounds__(256) k_normrope(const float* __restrict__ QKV,
    const float* __restrict__ cosT, const float* __restrict__ sinT,
    const float* __restrict__ q_gain, float* __restrict__ QP, float* __restrict__ KP) {
  int gid = blockIdx.x * 256 + threadIdx.x;
  int lane = gid & 63;
  int w = gid >> 6;            // wave id 0..131071
  int r = w >> 5;              // row 0..4095
  int u = w & 31;
  int isk = u >> 4, h = u & 15;
  float x = QKV[(size_t)r * 3072 + isk * 1024 + h * 64 + lane];
  float ss = x * x;
  #pragma unroll
  for (int off = 32; off >= 1; off >>= 1) ss += __shfl_xor(ss, off);
  float xn = x * rsqrtf(ss * (1.0f / 64.0f) + 1e-5f);
  int s = r & (SLEN - 1);
  int j = lane & 31;
  float c = cosT[s * 32 + j], sn = sinT[s * 32 + j];
  float other = __shfl_xor(xn, 32);
  // lane<32: x1*c + x2*s ; lane>=32: -x1*s + x2*c
  float o = (lane < 32) ? fmaf(xn, c, other * sn) : fmaf(xn, c, -other * sn);
  if (!isk) o *= q_gain[h];
  float* dst = isk ? KP : QP;
  dst[(size_t)r * 1024 + h * 64 + lane] = o;
}

// ---------------- fp32 one-pass flash attention, broadcast-from-global ------
// Tile = 64 q-rows, lane = q-row. K/V rows are wave-uniform -> read directly
// from global (L1/L2 broadcast), NO LDS in the K-loop, no barriers.
// Block = 512 thr = 2 groups x 4 waves; group 0 -> tile p, group 1 -> tile
// 31-p  => every block = exactly 33 chunks (uniform load balance).
// Waves split their tile's chunks mod 4; fixed softmax shift m=0 (scores
// bounded by rmsnorm); split-K partials combine additively via tiny LDS.
template<bool EDGE>
__device__ __forceinline__ void attn_chunk(const float* __restrict__ kb,
                                           const float* __restrict__ vb,
                                           const float* __restrict__ q,
                                           float* __restrict__ acc,
                                           float& l, int nvalid) {
  #pragma unroll 1
  for (int kc = 0; kc < 64; ++kc) {
    const float* kr = kb + (size_t)kc * 1024;
    const float* vr = vb + (size_t)kc * 3072;
    float4 k0 = *(const float4*)(kr +  0);
    float4 k1 = *(const float4*)(kr +  4);
    float4 k2 = *(const float4*)(kr +  8);
    float4 k3 = *(const float4*)(kr + 12);
    float4 k4 = *(const float4*)(kr + 16);
    float4 k5 = *(const float4*)(kr + 20);
    float4 k6 = *(const float4*)(kr + 24);
    float4 k7 = *(const float4*)(kr + 28);
    float4 v0 = *(const float4*)(vr +  0);
    float4 v1 = *(const float4*)(vr +  4);
    float4 v2 = *(const float4*)(vr +  8);
    float4 v3 = *(const float4*)(vr + 12);
    float4 v4 = *(const float4*)(vr + 16);
    float4 v5 = *(const float4*)(vr + 20);
    float4 v6 = *(const float4*)(vr + 24);
    float4 v7 = *(const float4*)(vr + 28);
    float s0 = 0.f, s1 = 0.f, s2 = 0.f, s3 = 0.f;
    s0 = fmaf(q[ 0], k0.x, s0); s0 = fmaf(q[ 1], k0.y, s0);
    s0 = fmaf(q[ 2], k0.z, s0); s0 = fmaf(q[ 3], k0.w, s0);
    s0 = fmaf(q[ 4], k1.x, s0); s0 = fmaf(q[ 5], k1.y, s0);
    s0 = fmaf(q[ 6], k1.z, s0); s0 = fmaf(q[ 7], k1.w, s0);
    s1 = fmaf(q[ 8], k2.x, s1); s1 = fmaf(q[ 9], k2.y, s1);
    s1 = fmaf(q[10], k2.z, s1); s1 = fmaf(q[11], k2.w, s1);
    s1 = fmaf(q[12], k3.x, s1); s1 = fmaf(q[13], k3.y, s1);
    s1 = fmaf(q[14], k3.z, s1); s1 = fmaf(q[15], k3.w, s1);
    s2 = fmaf(q[16], k4.x, s2); s2 = fmaf(q[17], k4.y, s2);
    s2 = fmaf(q[18], k4.z, s2); s2 = fmaf(q[19], k4.w, s2);
    s2 = fmaf(q[20], k5.x, s2); s2 = fmaf(q[21], k5.y, s2);
    s2 = fmaf(q[22], k5.z, s2); s2 = fmaf(q[23], k5.w, s2);
    s3 = fmaf(q[24], k6.x, s3); s3 = fmaf(q[25], k6.y, s3);
    s3 = fmaf(q[26], k6.z, s3); s3 = fmaf(q[27], k6.w, s3);
    s3 = fmaf(q[28], k7.x, s3); s3 = fmaf(q[29], k7.y, s3);
    s3 = fmaf(q[30], k7.z, s3); s3 = fmaf(q[31], k7.w, s3);
    float s = (s0 + s1) + (s2 + s3);
    float pr = exp2f(s);                 // log2e folded into q at load
    if (EDGE) pr = (kc < nvalid) ? pr : 0.0f;
    l += pr;
    acc[ 0] = fmaf(pr, v0.x, acc[ 0]); acc[ 1] = fmaf(pr, v0.y, acc[ 1]);
    acc[ 2] = fmaf(pr, v0.z, acc[ 2]); acc[ 3] = fmaf(pr, v0.w, acc[ 3]);
    acc[ 4] = fmaf(pr, v1.x, acc[ 4]); acc[ 5] = fmaf(pr, v1.y, acc[ 5]);
    acc[ 6] = fmaf(pr, v1.z, acc[ 6]); acc[ 7] = fmaf(pr, v1.w, acc[ 7]);
    acc[ 8] = fmaf(pr, v2.x, acc[ 8]); acc[ 9] = fmaf(pr, v2.y, acc[ 9]);
    acc[10] = fmaf(pr, v2.z, acc[10]); acc[11] = fmaf(pr, v2.w, acc[11]);
    acc[12] = fmaf(pr, v3.x, acc[12]); acc[13] = fmaf(pr, v3.y, acc[13]);
    acc[14] = fmaf(pr, v3.z, acc[14]); acc[15] = fmaf(pr, v3.w, acc[15]);
    acc[16] = fmaf(pr, v4.x, acc[16]); acc[17] = fmaf(pr, v4.y, acc[17]);
    acc[18] = fmaf(pr, v4.z, acc[18]); acc[19] = fmaf(pr, v4.w, acc[19]);
    acc[20] = fmaf(pr, v5.x, acc[20]); acc[21] = fmaf(pr, v5.y, acc[21]);
    acc[22] = fmaf(pr, v5.z, acc[22]); acc[23] = fmaf(pr, v5.w, acc[23]);
    acc[24] = fmaf(pr, v6.x, acc[24]); acc[25] = fmaf(pr, v6.y, acc[25]);
    acc[26] = fmaf(pr, v6.z, acc[26]); acc[27] = fmaf(pr, v6.w, acc[27]);
    acc[28] = fmaf(pr, v7.x, acc[28]); acc[29] = fmaf(pr, v7.y, acc[29]);
    acc[30] = fmaf(pr, v7.z, acc[30]); acc[31] = fmaf(pr, v7.w, acc[31]);
  }
}

__global__ void __launch_bounds__(512, 4) k_attn(const float* __restrict__ QP,
    const float* __restrict__ KP, const float* __restrict__ QKV,
    float* __restrict__ OH) {
  __shared__ float Lsh[2][4][64];       // 2 KB
  __shared__ float Osh[2][64][33];      // 16.9 KB (pad 33: pass writes 2-way)
  const int p = blockIdx.x, hh = blockIdx.y, b = blockIdx.z;
  const int h = hh & 15, half = hh >> 4;
  const int t = threadIdx.x;
  const int grp = t >> 8;               // 0 or 1
  const int g = (t >> 6) & 3;           // wave within group
  const int lane = t & 63;
  const int T = grp ? (31 - p) : p;     // 64-row tile index, pair sums to 33 chunks
  const int q0 = T * 64;
  const int qkcol = h * 64 + half * 32;
  const int vcol = 2048 + qkcol;
  const int row = q0 + lane;

  // Q row into registers with 1/sqrt(32)*log2(e) folded in
  float q[32];
  {
    const float qscale = 0.17677669529663687f * 1.4426950408889634f;
    const float* qp = QP + (size_t)(b * SLEN + row) * 1024 + qkcol;
    #pragma unroll
    for (int j = 0; j < 8; ++j) {
      float4 a = *(const float4*)(qp + 4 * j);
      q[4 * j + 0] = a.x * qscale; q[4 * j + 1] = a.y * qscale;
      q[4 * j + 2] = a.z * qscale; q[4 * j + 3] = a.w * qscale;
    }
  }
  float acc[32] = {};
  float l = 0.f;
  const float* Kbase = KP  + (size_t)(b * SLEN) * 1024 + qkcol;
  const float* Vbase = QKV + (size_t)(b * SLEN) * 3072 + vcol;

  for (int cc = g; cc <= T; cc += 4) {
    const int ccu = __builtin_amdgcn_readfirstlane(cc);
    const float* kb = Kbase + (size_t)(ccu * 64) * 1024;
    const float* vb = Vbase + (size_t)(ccu * 64) * 3072;
    if (ccu < T) attn_chunk<false>(kb, vb, q, acc, l, 64);
    else         attn_chunk<true >(kb, vb, q, acc, l, lane + 1);
  }

  // ---- split-K combine: l partials, then pass-based acc accumulation ----
  Lsh[grp][g][lane] = l;
  __syncthreads();
  #pragma unroll
  for (int pp = 0; pp < 4; ++pp) {
    if (g == pp) {
      if (pp == 0) {
        #pragma unroll
        for (int j = 0; j < 32; ++j) Osh[grp][lane][j] = acc[j];
      } else {
        #pragma unroll
        for (int j = 0; j < 32; ++j) Osh[grp][lane][j] += acc[j];
      }
    }
    __syncthreads();
  }
  // write out: 256 threads per group, 8 floats each
  {
    const int tt = t & 255;
    const int r = tt >> 2;
    const int dq = (tt & 3) * 8;
    float ls = Lsh[grp][0][r] + Lsh[grp][1][r] + Lsh[grp][2][r] + Lsh[grp][3][r];
    float inv = 1.0f / ls;
    size_t gr = ((size_t)(b * SLEN + q0 + r) * 32 + hh) * 32 + dq;
    float4 o0 = {Osh[grp][r][dq + 0] * inv, Osh[grp][r][dq + 1] * inv,
                 Osh[grp][r][dq + 2] * inv, Osh[grp][r][dq + 3] * inv};
    float4 o1 = {Osh[grp][r][dq + 4] * inv, Osh[grp][r][dq + 5] * inv,
                 Osh[grp][r][dq + 6] * inv, Osh[grp][r][dq + 7] * inv};
    *(float4*)(OH + gr)     = o0;
    *(float4*)(OH + gr + 4) = o1;
  }
}

// ---------------- differential combine: y = [y1 - lam*y2, y1 + lam*y2] -------
__global__ void __launch_bounds__(256) k_combine(const float* __restrict__ OH,
    const float* __restrict__ dl, float* __restrict__ Y) {
  int idx = blockIdx.x * 256 + threadIdx.x;   // 4096*16*32
  int d = idx & 31;
  int h = (idx >> 5) & 15;
  int r = idx >> 9;
  float y1 = OH[((size_t)r * 32 + h) * 32 + d];
  float y2 = OH[((size_t)r * 32 + h + 16) * 32 + d];
  float lam = dl[h];
  Y[(size_t)r * 1024 + h * 64 + d]      = y1 - lam * y2;
  Y[(size_t)r * 1024 + h * 64 + 32 + d] = y1 + lam * y2;
}

// ---------------- prototype projection -> A1T[f][o], A2T[f][o] ----------------
__global__ void __launch_bounds__(256) k_protproj(const float* __restrict__ PT,
    const float* __restrict__ features, const float* __restrict__ thp,
    const float* __restrict__ alp, const float* __restrict__ bep,
    float* __restrict__ A1T, float* __restrict__ A2T) {
  int o = blockIdx.x, t = threadIdx.x;
  int f = t >> 4, seg = t & 15;
  const float* pr = PT + (size_t)o * 1024 + seg * 64;
  const float* fr = features + (size_t)f * 1024 + seg * 64;
  float acc = 0.0f;
  #pragma unroll
  for (int i = 0; i < 64; i += 4) {
    float4 a = *(const float4*)(pr + i);
    float4 bq = *(const float4*)(fr + i);
    acc = fmaf(a.x, bq.x, acc); acc = fmaf(a.y, bq.y, acc);
    acc = fmaf(a.z, bq.z, acc); acc = fmaf(a.w, bq.w, acc);
  }
  acc += __shfl_xor(acc, 1); acc += __shfl_xor(acc, 2);
  acc += __shfl_xor(acc, 4); acc += __shfl_xor(acc, 8);
  if (seg == 0) {
    float pf = acc;
    float ps = 1.0f / (1.0f + expf(-5.0f * pf));
    float pa = pf * ps;
    A1T[f * 1024 + o] = fabsf(*thp) * pa - fabsf(*alp) * (1.0f - ps);
    A2T[f * 1024 + o] = -fabsf(*bep) * pa;
  }
}

// ---------------- x features: x_a and (1-x_s) ----------------
__global__ void __launch_bounds__(256) k_xfeat(const float* __restrict__ Y,
    const float* __restrict__ features, float* __restrict__ XA, float* __restrict__ XS1) {
  int r = blockIdx.x, t = threadIdx.x;
  int f = t >> 4, seg = t & 15;
  const float* yr = Y + (size_t)r * 1024 + seg * 64;
  const float* fr = features + (size_t)f * 1024 + seg * 64;
  float acc = 0.0f;
  #pragma unroll
  for (int i = 0; i < 64; i += 4) {
    float4 a = *(const float4*)(yr + i);
    float4 bq = *(const float4*)(fr + i);
    acc = fmaf(a.x, bq.x, acc); acc = fmaf(a.y, bq.y, acc);
    acc = fmaf(a.z, bq.z, acc); acc = fmaf(a.w, bq.w, acc);
  }
  acc += __shfl_xor(acc, 1); acc += __shfl_xor(acc, 2);
  acc += __shfl_xor(acc, 4); acc += __shfl_xor(acc, 8);
  if (seg == 0) {
    float xf = acc;
    float xs = 1.0f / (1.0f + expf(-5.0f * xf));
    XA[r * 16 + f] = xf * xs;
    XS1[r * 16 + f] = 1.0f - xs;
  }
}

// ---------------- final: out = XA @ A1T + XS1 @ A2T ----------------
__global__ void __launch_bounds__(256) k_final(const float* __restrict__ XA,
    const float* __restrict__ XS1, const float* __restrict__ A1T,
    const float* __restrict__ A2T, float* __restrict__ out) {
  int r = blockIdx.x, t = threadIdx.x;
  float xa[16], x1[16];
  #pragma unroll
  for (int f4 = 0; f4 < 16; f4 += 4) {
    float4 a = *(const float4*)(XA + r * 16 + f4);
    float4 b = *(const float4*)(XS1 + r * 16 + f4);
    xa[f4] = a.x; xa[f4 + 1] = a.y; xa[f4 + 2] = a.z; xa[f4 + 3] = a.w;
    x1[f4] = b.x; x1[f4 + 1] = b.y; x1[f4 + 2] = b.z; x1[f4 + 3] = b.w;
  }
  float4 acc = {0.f, 0.f, 0.f, 0.f};
  #pragma unroll
  for (int f = 0; f < 16; ++f) {
    float4 a1 = *(const float4*)(A1T + f * 1024 + t * 4);
    float4 a2 = *(const float4*)(A2T + f * 1024 + t * 4);
    acc.x = fmaf(xa[f], a1.x, fmaf(x1[f], a2.x, acc.x));
    acc.y = fmaf(xa[f], a1.y, fmaf(x1[f], a2.y, acc.y));
    acc.z = fmaf(xa[f], a1.z, fmaf(x1[f], a2.z, acc.z));
    acc.w = fmaf(xa[f], a1.w, fmaf(x1[f], a2.w, acc.w));
  }
  *(float4*)(out + (size_t)r * 1024 + t * 4) = acc;
}

extern "C" void kernel_launch(void* const* d_in, const int* in_sizes, int n_in,
                              void* d_out, int out_size, void* d_ws, size_t ws_size,
                              hipStream_t stream) {
  const float* x      = (const float*)d_in[0];
  const float* w_qkv  = (const float*)d_in[1];
  const float* feats  = (const float*)d_in[2];
  const float* protos = (const float*)d_in[3];
  const float* theta  = (const float*)d_in[4];
  const float* alpha  = (const float*)d_in[5];
  const float* beta   = (const float*)d_in[6];
  const float* q_gain = (const float*)d_in[7];
  const float* dlam   = (const float*)d_in[8];
  float* out = (float*)d_out;
  float* ws  = (float*)d_ws;

  // workspace layout (floats)
  float* W_T = ws;                    // 3,145,728
  float* QKV = W_T + 3145728;         // 12,582,912
  float* QP  = QKV + 12582912;        // 4,194,304
  float* KP  = QP  + 4194304;         // 4,194,304
  float* OH  = KP  + 4194304;         // 4,194,304
  float* Y   = OH  + 4194304;         // 4,194,304
  float* COS = Y   + 4194304;         // 65,536
  float* SIN = COS + 65536;           // 65,536
  float* PT  = SIN + 65536;           // 1,048,576
  float* A1T = PT  + 1048576;         // 16,384
  float* A2T = A1T + 16384;           // 16,384
  float* XA  = A2T + 16384;           // 65,536
  float* XS1 = XA  + 65536;           // 65,536

  k_rope_tab<<<256, 256, 0, stream>>>(COS, SIN);
  k_ternary<<<12288, 256, 0, stream>>>(w_qkv, W_T);     // 3,145,728 elems
  k_ternary<<<4096, 256, 0, stream>>>(protos, PT);      // 1,048,576 elems
  dim3 gg(QKV_N / 128, NROWS / 128);
  k_gemm_nt<<<gg, 256, 0, stream>>>(x, W_T, QKV, NROWS, QKV_N, DIM);
  k_normrope<<<32768, 256, 0, stream>>>(QKV, COS, SIN, q_gain, QP, KP);
  dim3 ga(16, 32, BATCH);
  k_attn<<<ga, 512, 0, stream>>>(QP, KP, QKV, OH);
  k_combine<<<8192, 256, 0, stream>>>(OH, dlam, Y);
  k_protproj<<<1024, 256, 0, stream>>>(PT, feats, theta, alpha, beta, A1T, A2T);
  k_xfeat<<<4096, 256, 0, stream>>>(Y, feats, XA, XS1);
  k_final<<<4096, 256, 0, stream>>>(XA, XS1, A1T, A2T, out);
}

// Round 4
// 606.901 us; speedup vs baseline: 1.6247x; 1.6247x over previous
//
#include <hip/hip_runtime.h>
#include <hip/hip_bf16.h>
#include <math.h>

// Problem constants
#define DIM   1024
#define NHEAD 16
#define SLEN  2048
#define BATCH 2
#define NROWS (BATCH*SLEN)   // 4096
#define QKV_N 3072

typedef __attribute__((ext_vector_type(8))) short short8v;
typedef __attribute__((ext_vector_type(4))) short short4v;
typedef __attribute__((ext_vector_type(4))) float f32x4;

__device__ __forceinline__ float bfr(float x) {
  return __bfloat162float(__float2bfloat16(x));
}
__device__ __forceinline__ unsigned short f2bf(float f) {
  __hip_bfloat16 h = __float2bfloat16(f);
  unsigned short u;
  __builtin_memcpy(&u, &h, 2);
  return u;
}

// ---------------- rope tables (match numpy f32 semantics) ----------------
__global__ void __launch_bounds__(256) k_rope_tab(float* __restrict__ cosT,
                                                  float* __restrict__ sinT) {
  int idx = blockIdx.x * 256 + threadIdx.x;        // 2048*32 = 65536
  int s = idx >> 5, j = idx & 31;
  double inv  = 1.0 / pow(10000.0, (double)(2 * j) / 64.0);
  double ramp = ((double)(2 * j) / 64.0 - 0.25) / 0.75;
  ramp = ramp < 0.0 ? 0.0 : (ramp > 1.0 ? 1.0 : ramp);
  inv /= (ramp * 3.0 + 1.0);                       // yarn: 1/scale - 1 = 3
  float freq = (float)s * (float)inv;              // f32 product like reference
  cosT[idx] = (float)cos((double)freq);
  sinT[idx] = (float)sin((double)freq);
}

// ---------------- ternary quantization (bf16-faithful) ----------------
__global__ void __launch_bounds__(256) k_ternary(const float* __restrict__ in,
                                                 float* __restrict__ out) {
  int idx = blockIdx.x * 256 + threadIdx.x;
  float wb = bfr(in[idx]);
  float a = fabsf(wb);
  #pragma unroll
  for (int off = 32; off >= 1; off >>= 1) a += __shfl_xor(a, off);
  float scale = bfr(a * (1.0f / 64.0f));
  scale = fmaxf(scale, 1e-8f);
  float ratio = bfr(wb / scale);
  float q = rintf(ratio);
  q = fminf(1.0f, fmaxf(-1.0f, q));
  float deq = bfr(q * scale);
  float d = bfr(deq - wb);
  out[idx] = bfr(wb + d);
}

// ---------------- fp32 GEMM  C[M,N] = A[M,K] * B[N,K]^T ----------------
__global__ void __launch_bounds__(256) k_gemm_nt(const float* __restrict__ A,
                                                 const float* __restrict__ B,
                                                 float* __restrict__ C,
                                                 int M, int N, int K) {
  __shared__ float As[16][132];
  __shared__ float Bs[16][132];
  const int t = threadIdx.x;
  const int bm = blockIdx.y * 128, bn = blockIdx.x * 128;
  const int tx = t & 15, ty = t >> 4;
  float acc[8][8] = {};
  for (int k0 = 0; k0 < K; k0 += 16) {
    #pragma unroll
    for (int l = 0; l < 2; ++l) {
      int f = l * 1024 + t * 4;
      int r = f >> 4, c = f & 15;
      float4 va = *(const float4*)(A + (size_t)(bm + r) * K + k0 + c);
      As[c + 0][r] = va.x; As[c + 1][r] = va.y; As[c + 2][r] = va.z; As[c + 3][r] = va.w;
      float4 vb = *(const float4*)(B + (size_t)(bn + r) * K + k0 + c);
      Bs[c + 0][r] = vb.x; Bs[c + 1][r] = vb.y; Bs[c + 2][r] = vb.z; Bs[c + 3][r] = vb.w;
    }
    __syncthreads();
    #pragma unroll
    for (int kk = 0; kk < 16; ++kk) {
      float4 a0 = *(const float4*)&As[kk][ty * 8];
      float4 a1 = *(const float4*)&As[kk][ty * 8 + 4];
      float4 b0 = *(const float4*)&Bs[kk][tx * 8];
      float4 b1 = *(const float4*)&Bs[kk][tx * 8 + 4];
      float av[8] = {a0.x, a0.y, a0.z, a0.w, a1.x, a1.y, a1.z, a1.w};
      float bv[8] = {b0.x, b0.y, b0.z, b0.w, b1.x, b1.y, b1.z, b1.w};
      #pragma unroll
      for (int i = 0; i < 8; ++i)
        #pragma unroll
        for (int j = 0; j < 8; ++j)
          acc[i][j] = fmaf(av[i], bv[j], acc[i][j]);
    }
    __syncthreads();
  }
  #pragma unroll
  for (int i = 0; i < 8; ++i) {
    float4 o0 = {acc[i][0], acc[i][1], acc[i][2], acc[i][3]};
    float4 o1 = {acc[i][4], acc[i][5], acc[i][6], acc[i][7]};
    *(float4*)(C + (size_t)(bm + ty * 8 + i) * N + bn + tx * 8) = o0;
    *(float4*)(C + (size_t)(bm + ty * 8 + i) * N + bn + tx * 8 + 4) = o1;
  }
}

// ---------------- rmsnorm + rope + q_gain -> bf16 [b][hh][s][32] ------------
// one wave per (row, {q-head or k-head}); lane = dim 0..63
// Q gets softmax scale (1/sqrt(32) * log2(e)) folded in.
__global__ void __launch_bounds__(256) k_normrope(const float* __restrict__ QKV,
    const float* __restrict__ cosT, const float* __restrict__ sinT,
    const float* __restrict__ q_gain,
    unsigned short* __restrict__ QB16, unsigned short* __restrict__ KB16) {
  int gid = blockIdx.x * 256 + threadIdx.x;
  int lane = gid & 63;
  int w = gid >> 6;            // wave id 0..131071
  int r = w >> 5;              // row 0..4095
  int u = w & 31;
  int isk = u >> 4, h = u & 15;
  float x = QKV[(size_t)r * 3072 + isk * 1024 + h * 64 + lane];
  float ss = x * x;
  #pragma unroll
  for (int off = 32; off >= 1; off >>= 1) ss += __shfl_xor(ss, off);
  float xn = x * rsqrtf(ss * (1.0f / 64.0f) + 1e-5f);
  int s = r & (SLEN - 1);
  int b = r >> 11;
  int j = lane & 31;
  float c = cosT[s * 32 + j], sn = sinT[s * 32 + j];
  float other = __shfl_xor(xn, 32);
  float o = (lane < 32) ? fmaf(xn, c, other * sn) : fmaf(xn, c, -other * sn);
  int hh = h + 16 * (lane >> 5);
  int dd = lane & 31;
  size_t addr = (((size_t)(b * 32 + hh) * SLEN) + s) * 32 + dd;
  if (!isk) {
    const float FOLD = 0.17677669529663687f * 1.4426950408889634f;
    QB16[addr] = f2bf(o * q_gain[h] * FOLD);
  } else {
    KB16[addr] = f2bf(o);
  }
}

// ---------------- V transpose -> bf16 VT16 [b][hh][d=32][s=2048] ------------
__global__ void __launch_bounds__(256) k_vtrans(const float* __restrict__ QKV,
                                                unsigned short* __restrict__ VT16) {
  __shared__ short Vt[64][34];
  const int s0 = blockIdx.x * 64, hh = blockIdx.y, b = blockIdx.z;
  const int vcb = 2048 + (hh & 15) * 64 + (hh >> 4) * 32;
  const int t = threadIdx.x;
  {
    int row = t >> 2, dpart = (t & 3) * 8;
    const float* p = QKV + (size_t)(b * SLEN + s0 + row) * 3072 + vcb + dpart;
    float4 a = *(const float4*)p;
    float4 bq = *(const float4*)(p + 4);
    Vt[row][dpart + 0] = (short)f2bf(a.x);  Vt[row][dpart + 1] = (short)f2bf(a.y);
    Vt[row][dpart + 2] = (short)f2bf(a.z);  Vt[row][dpart + 3] = (short)f2bf(a.w);
    Vt[row][dpart + 4] = (short)f2bf(bq.x); Vt[row][dpart + 5] = (short)f2bf(bq.y);
    Vt[row][dpart + 6] = (short)f2bf(bq.z); Vt[row][dpart + 7] = (short)f2bf(bq.w);
  }
  __syncthreads();
  {
    int d = t >> 3, spart = (t & 7) * 8;
    short8v v;
    #pragma unroll
    for (int i = 0; i < 8; ++i) v[i] = Vt[spart + i][d];
    *(short8v*)(VT16 + (((size_t)(b * 32 + hh) * 32) + d) * SLEN + s0 + spart) = v;
  }
}

// ---------------- MFMA flash attention (bf16, 16x16x32) ---------------------
// One wave per (b, hh, 16-row q-tile). No __syncthreads anywhere: per-wave
// private LDS for the P C-layout -> B-layout transform.
// S^T = K·Q^T (A=K frag, B=Q frag); O^T = V^T·P^T (A=V^T frag, B=P frag).
// Fixed softmax shift m=0 (scores bounded by rmsnorm).
__global__ void __launch_bounds__(256) k_attn(
    const unsigned short* __restrict__ QB16,
    const unsigned short* __restrict__ KB16,
    const unsigned short* __restrict__ VT16,
    float* __restrict__ OH) {
  __shared__ short Plds[4][16 * 32];     // per-wave 1 KB
  const int fid = blockIdx.x;            // 2048 blocks
  const int combo = fid & 63;            // same-(b,hh) blocks share fid%8 -> XCD
  const int p = fid >> 6;                // 0..31
  const int b = combo >> 5, hh = combo & 31;
  const int t = threadIdx.x;
  const int w = t >> 6, lane = t & 63;
  const int qL = lane & 15, quad = lane >> 4;
  int qt;                                 // balanced: chunk counts sum = 130
  if (w == 0) qt = p; else if (w == 1) qt = 63 - p;
  else if (w == 2) qt = 64 + p; else qt = 127 - p;
  const int q0 = qt * 16;
  const int qg = q0 + qL;

  const unsigned short* QB = QB16 + (size_t)(b * 32 + hh) * SLEN * 32;
  const unsigned short* KB = KB16 + (size_t)(b * 32 + hh) * SLEN * 32;
  const unsigned short* VT = VT16 + (size_t)(b * 32 + hh) * 32 * SLEN;

  const short8v qf = *(const short8v*)(QB + ((size_t)(q0 + qL) << 5) + (quad << 3));
  f32x4 acc0 = {0.f, 0.f, 0.f, 0.f};
  f32x4 acc1 = {0.f, 0.f, 0.f, 0.f};
  const f32x4 zz = {0.f, 0.f, 0.f, 0.f};
  float l = 0.f;
  short* Pw = &Plds[w][0];
  const int pws = (qL << 5) + (quad << 2);   // short4 store offset (tile0)
  const int pwr = (qL << 5) + (quad << 3);   // short8 read offset

  const int nch = (qt >> 1) + 1;
  for (int c = 0; c < nch; ++c) {
    const int k0 = c * 32;
    const unsigned short* kp = KB + ((size_t)(k0 + qL) << 5) + (quad << 3);
    short8v kf0 = *(const short8v*)kp;
    short8v kf1 = *(const short8v*)(kp + (16 << 5));
    const unsigned short* vp = VT + ((size_t)qL << 11) + k0 + (quad << 3);
    short8v vf0 = *(const short8v*)vp;
    short8v vf1 = *(const short8v*)(vp + (16 << 11));
    f32x4 st0 = __builtin_amdgcn_mfma_f32_16x16x32_bf16(kf0, qf, zz, 0, 0, 0);
    f32x4 st1 = __builtin_amdgcn_mfma_f32_16x16x32_bf16(kf1, qf, zz, 0, 0, 0);
    short4v pk0, pk1;
    if (c == nch - 1) {                      // masked tail (covers diagonal)
      const int kb0 = k0 + (quad << 2);
      #pragma unroll
      for (int r = 0; r < 4; ++r) {
        float pr = (kb0 + r <= qg) ? exp2f(st0[r]) : 0.f;
        l += pr; pk0[r] = (short)f2bf(pr);
      }
      #pragma unroll
      for (int r = 0; r < 4; ++r) {
        float pr = (kb0 + 16 + r <= qg) ? exp2f(st1[r]) : 0.f;
        l += pr; pk1[r] = (short)f2bf(pr);
      }
    } else {
      #pragma unroll
      for (int r = 0; r < 4; ++r) {
        float pr = exp2f(st0[r]); l += pr; pk0[r] = (short)f2bf(pr);
      }
      #pragma unroll
      for (int r = 0; r < 4; ++r) {
        float pr = exp2f(st1[r]); l += pr; pk1[r] = (short)f2bf(pr);
      }
    }
    *(short4v*)(Pw + pws)      = pk0;        // P^T[k][q] stored as Plds[q][k]
    *(short4v*)(Pw + pws + 16) = pk1;
    short8v pf = *(const short8v*)(Pw + pwr);
    acc0 = __builtin_amdgcn_mfma_f32_16x16x32_bf16(vf0, pf, acc0, 0, 0, 0);
    acc1 = __builtin_amdgcn_mfma_f32_16x16x32_bf16(vf1, pf, acc1, 0, 0, 0);
  }
  // reduce l across quads (lanes sharing qL)
  l += __shfl_xor(l, 16);
  l += __shfl_xor(l, 32);
  const float inv = 1.0f / l;
  // O^T C-layout: lane holds (q=qL, d = 16*half + quad*4 + r)
  float* ob = OH + (((size_t)(b * SLEN + q0 + qL) * 32) + hh) * 32 + (quad << 2);
  float4 o0 = {acc0[0] * inv, acc0[1] * inv, acc0[2] * inv, acc0[3] * inv};
  float4 o1 = {acc1[0] * inv, acc1[1] * inv, acc1[2] * inv, acc1[3] * inv};
  *(float4*)ob        = o0;
  *(float4*)(ob + 16) = o1;
}

// ---------------- differential combine: y = [y1 - lam*y2, y1 + lam*y2] -------
__global__ void __launch_bounds__(256) k_combine(const float* __restrict__ OH,
    const float* __restrict__ dl, float* __restrict__ Y) {
  int idx = blockIdx.x * 256 + threadIdx.x;   // 4096*16*32
  int d = idx & 31;
  int h = (idx >> 5) & 15;
  int r = idx >> 9;
  float y1 = OH[((size_t)r * 32 + h) * 32 + d];
  float y2 = OH[((size_t)r * 32 + h + 16) * 32 + d];
  float lam = dl[h];
  Y[(size_t)r * 1024 + h * 64 + d]      = y1 - lam * y2;
  Y[(size_t)r * 1024 + h * 64 + 32 + d] = y1 + lam * y2;
}

// ---------------- prototype projection -> A1T[f][o], A2T[f][o] ----------------
__global__ void __launch_bounds__(256) k_protproj(const float* __restrict__ PT,
    const float* __restrict__ features, const float* __restrict__ thp,
    const float* __restrict__ alp, const float* __restrict__ bep,
    float* __restrict__ A1T, float* __restrict__ A2T) {
  int o = blockIdx.x, t = threadIdx.x;
  int f = t >> 4, seg = t & 15;
  const float* pr = PT + (size_t)o * 1024 + seg * 64;
  const float* fr = features + (size_t)f * 1024 + seg * 64;
  float acc = 0.0f;
  #pragma unroll
  for (int i = 0; i < 64; i += 4) {
    float4 a = *(const float4*)(pr + i);
    float4 bq = *(const float4*)(fr + i);
    acc = fmaf(a.x, bq.x, acc); acc = fmaf(a.y, bq.y, acc);
    acc = fmaf(a.z, bq.z, acc); acc = fmaf(a.w, bq.w, acc);
  }
  acc += __shfl_xor(acc, 1); acc += __shfl_xor(acc, 2);
  acc += __shfl_xor(acc, 4); acc += __shfl_xor(acc, 8);
  if (seg == 0) {
    float pf = acc;
    float ps = 1.0f / (1.0f + expf(-5.0f * pf));
    float pa = pf * ps;
    A1T[f * 1024 + o] = fabsf(*thp) * pa - fabsf(*alp) * (1.0f - ps);
    A2T[f * 1024 + o] = -fabsf(*bep) * pa;
  }
}

// ---------------- x features: x_a and (1-x_s) ----------------
__global__ void __launch_bounds__(256) k_xfeat(const float* __restrict__ Y,
    const float* __restrict__ features, float* __restrict__ XA, float* __restrict__ XS1) {
  int r = blockIdx.x, t = threadIdx.x;
  int f = t >> 4, seg = t & 15;
  const float* yr = Y + (size_t)r * 1024 + seg * 64;
  const float* fr = features + (size_t)f * 1024 + seg * 64;
  float acc = 0.0f;
  #pragma unroll
  for (int i = 0; i < 64; i += 4) {
    float4 a = *(const float4*)(yr + i);
    float4 bq = *(const float4*)(fr + i);
    acc = fmaf(a.x, bq.x, acc); acc = fmaf(a.y, bq.y, acc);
    acc = fmaf(a.z, bq.z, acc); acc = fmaf(a.w, bq.w, acc);
  }
  acc += __shfl_xor(acc, 1); acc += __shfl_xor(acc, 2);
  acc += __shfl_xor(acc, 4); acc += __shfl_xor(acc, 8);
  if (seg == 0) {
    float xf = acc;
    float xs = 1.0f / (1.0f + expf(-5.0f * xf));
    XA[r * 16 + f] = xf * xs;
    XS1[r * 16 + f] = 1.0f - xs;
  }
}

// ---------------- final: out = XA @ A1T + XS1 @ A2T ----------------
__global__ void __launch_bounds__(256) k_final(const float* __restrict__ XA,
    const float* __restrict__ XS1, const float* __restrict__ A1T,
    const float* __restrict__ A2T, float* __restrict__ out) {
  int r = blockIdx.x, t = threadIdx.x;
  float xa[16], x1[16];
  #pragma unroll
  for (int f4 = 0; f4 < 16; f4 += 4) {
    float4 a = *(const float4*)(XA + r * 16 + f4);
    float4 b = *(const float4*)(XS1 + r * 16 + f4);
    xa[f4] = a.x; xa[f4 + 1] = a.y; xa[f4 + 2] = a.z; xa[f4 + 3] = a.w;
    x1[f4] = b.x; x1[f4 + 1] = b.y; x1[f4 + 2] = b.z; x1[f4 + 3] = b.w;
  }
  float4 acc = {0.f, 0.f, 0.f, 0.f};
  #pragma unroll
  for (int f = 0; f < 16; ++f) {
    float4 a1 = *(const float4*)(A1T + f * 1024 + t * 4);
    float4 a2 = *(const float4*)(A2T + f * 1024 + t * 4);
    acc.x = fmaf(xa[f], a1.x, fmaf(x1[f], a2.x, acc.x));
    acc.y = fmaf(xa[f], a1.y, fmaf(x1[f], a2.y, acc.y));
    acc.z = fmaf(xa[f], a1.z, fmaf(x1[f], a2.z, acc.z));
    acc.w = fmaf(xa[f], a1.w, fmaf(x1[f], a2.w, acc.w));
  }
  *(float4*)(out + (size_t)r * 1024 + t * 4) = acc;
}

extern "C" void kernel_launch(void* const* d_in, const int* in_sizes, int n_in,
                              void* d_out, int out_size, void* d_ws, size_t ws_size,
                              hipStream_t stream) {
  const float* x      = (const float*)d_in[0];
  const float* w_qkv  = (const float*)d_in[1];
  const float* feats  = (const float*)d_in[2];
  const float* protos = (const float*)d_in[3];
  const float* theta  = (const float*)d_in[4];
  const float* alpha  = (const float*)d_in[5];
  const float* beta   = (const float*)d_in[6];
  const float* q_gain = (const float*)d_in[7];
  const float* dlam   = (const float*)d_in[8];
  float* out = (float*)d_out;
  float* ws  = (float*)d_ws;

  // workspace layout (floats); total ~31.7M floats = 126.7 MB
  float* W_T = ws;                    // 3,145,728
  float* QKV = W_T + 3145728;         // 12,582,912
  float* OH  = QKV + 12582912;        // 4,194,304
  float* Y   = OH  + 4194304;         // 4,194,304
  float* COS = Y   + 4194304;         // 65,536
  float* SIN = COS + 65536;           // 65,536
  float* PT  = SIN + 65536;           // 1,048,576
  float* A1T = PT  + 1048576;         // 16,384
  float* A2T = A1T + 16384;           // 16,384
  float* XA  = A2T + 16384;           // 65,536
  float* XS1 = XA  + 65536;           // 65,536
  unsigned short* QB16 = (unsigned short*)(XS1 + 65536);  // 4,194,304 shorts
  unsigned short* KB16 = QB16 + 4194304;                  // 4,194,304 shorts
  unsigned short* VT16 = KB16 + 4194304;                  // 4,194,304 shorts

  k_rope_tab<<<256, 256, 0, stream>>>(COS, SIN);
  k_ternary<<<12288, 256, 0, stream>>>(w_qkv, W_T);
  k_ternary<<<4096, 256, 0, stream>>>(protos, PT);
  dim3 gg(QKV_N / 128, NROWS / 128);
  k_gemm_nt<<<gg, 256, 0, stream>>>(x, W_T, QKV, NROWS, QKV_N, DIM);
  k_normrope<<<32768, 256, 0, stream>>>(QKV, COS, SIN, q_gain, QB16, KB16);
  dim3 gv(SLEN / 64, 32, BATCH);
  k_vtrans<<<gv, 256, 0, stream>>>(QKV, VT16);
  k_attn<<<2048, 256, 0, stream>>>(QB16, KB16, VT16, OH);
  k_combine<<<8192, 256, 0, stream>>>(OH, dlam, Y);
  k_protproj<<<1024, 256, 0, stream>>>(PT, feats, theta, alpha, beta, A1T, A2T);
  k_xfeat<<<4096, 256, 0, stream>>>(Y, feats, XA, XS1);
  k_final<<<4096, 256, 0, stream>>>(XA, XS1, A1T, A2T, out);
}

// Round 5
// 377.314 us; speedup vs baseline: 2.6133x; 1.6085x over previous
//
#include <hip/hip_runtime.h>
#include <hip/hip_bf16.h>
#include <math.h>

// Problem constants
#define DIM   1024
#define NHEAD 16
#define SLEN  2048
#define BATCH 2
#define NROWS (BATCH*SLEN)   // 4096
#define QKV_N 3072

typedef __attribute__((ext_vector_type(8))) short short8v;
typedef __attribute__((ext_vector_type(4))) short short4v;
typedef __attribute__((ext_vector_type(4))) float f32x4;

__device__ __forceinline__ float bfr(float x) {
  return __bfloat162float(__float2bfloat16(x));
}
__device__ __forceinline__ unsigned short f2bf(float f) {
  __hip_bfloat16 h = __float2bfloat16(f);
  unsigned short u;
  __builtin_memcpy(&u, &h, 2);
  return u;
}
__device__ __forceinline__ float bf2f(unsigned short u) {
  __hip_bfloat16 h;
  __builtin_memcpy(&h, &u, 2);
  return __bfloat162float(h);
}

// async global->LDS, 16 bytes per lane; LDS dest = wave-uniform base + lane*16
__device__ __forceinline__ void gld16(const unsigned short* g, unsigned short* l) {
  __builtin_amdgcn_global_load_lds(
      (const __attribute__((address_space(1))) unsigned int*)g,
      (__attribute__((address_space(3))) unsigned int*)l, 16, 0, 0);
}

// ---------------- rope tables (match numpy f32 semantics) ----------------
__global__ void __launch_bounds__(256) k_rope_tab(float* __restrict__ cosT,
                                                  float* __restrict__ sinT) {
  int idx = blockIdx.x * 256 + threadIdx.x;        // 2048*32 = 65536
  int s = idx >> 5, j = idx & 31;
  double inv  = 1.0 / pow(10000.0, (double)(2 * j) / 64.0);
  double ramp = ((double)(2 * j) / 64.0 - 0.25) / 0.75;
  ramp = ramp < 0.0 ? 0.0 : (ramp > 1.0 ? 1.0 : ramp);
  inv /= (ramp * 3.0 + 1.0);                       // yarn: 1/scale - 1 = 3
  float freq = (float)s * (float)inv;              // f32 product like reference
  cosT[idx] = (float)cos((double)freq);
  sinT[idx] = (float)sin((double)freq);
}

// ---------------- ternary quantization (bf16-faithful) ----------------
// one 64-lane wave per group of 64 consecutive elements; fp32 output
__global__ void __launch_bounds__(256) k_ternary(const float* __restrict__ in,
                                                 float* __restrict__ out) {
  int idx = blockIdx.x * 256 + threadIdx.x;
  float wb = bfr(in[idx]);
  float a = fabsf(wb);
  #pragma unroll
  for (int off = 32; off >= 1; off >>= 1) a += __shfl_xor(a, off);
  float scale = bfr(a * (1.0f / 64.0f));
  scale = fmaxf(scale, 1e-8f);
  float ratio = bfr(wb / scale);
  float q = rintf(ratio);
  q = fminf(1.0f, fmaxf(-1.0f, q));
  float deq = bfr(q * scale);
  float d = bfr(deq - wb);
  out[idx] = bfr(wb + d);
}

// same, bf16 output (value is exactly bf16-representable)
__global__ void __launch_bounds__(256) k_ternary_bf16(const float* __restrict__ in,
                                                      unsigned short* __restrict__ out) {
  int idx = blockIdx.x * 256 + threadIdx.x;
  float wb = bfr(in[idx]);
  float a = fabsf(wb);
  #pragma unroll
  for (int off = 32; off >= 1; off >>= 1) a += __shfl_xor(a, off);
  float scale = bfr(a * (1.0f / 64.0f));
  scale = fmaxf(scale, 1e-8f);
  float ratio = bfr(wb / scale);
  float q = rintf(ratio);
  q = fminf(1.0f, fmaxf(-1.0f, q));
  float deq = bfr(q * scale);
  float d = bfr(deq - wb);
  out[idx] = f2bf(wb + d);
}

// ---------------- split x into hi/lo bf16 (fp32-faithful pair) ----------------
__global__ void __launch_bounds__(256) k_xsplit(const float* __restrict__ x,
    unsigned short* __restrict__ Xhi, unsigned short* __restrict__ Xlo) {
  int idx = blockIdx.x * 256 + threadIdx.x;      // 1,048,576 threads x 4 elems
  float4 v = *(const float4*)(x + (size_t)idx * 4);
  short4v hi, lo;
  float h0 = bfr(v.x); hi[0] = (short)f2bf(v.x); lo[0] = (short)f2bf(v.x - h0);
  float h1 = bfr(v.y); hi[1] = (short)f2bf(v.y); lo[1] = (short)f2bf(v.y - h1);
  float h2 = bfr(v.z); hi[2] = (short)f2bf(v.z); lo[2] = (short)f2bf(v.z - h2);
  float h3 = bfr(v.w); hi[3] = (short)f2bf(v.w); lo[3] = (short)f2bf(v.w - h3);
  *(short4v*)(Xhi + (size_t)idx * 4) = hi;
  *(short4v*)(Xlo + (size_t)idx * 4) = lo;
}

// ---------------- bf16 MFMA GEMM: C[M=4096][N=3072] = (Xhi+Xlo)·Wb^T --------
// 128x128 tile, BK=32, 256 thr = 4 waves (2x2), wave = 4x4 frags of 16x16x32.
// A operand split-bf16 (hi+lo) -> fp32-faithful; B (ternary weights) exact.
__global__ void __launch_bounds__(256) k_gemm_mfma(
    const unsigned short* __restrict__ Xhi, const unsigned short* __restrict__ Xlo,
    const unsigned short* __restrict__ Wb, float* __restrict__ C) {
  __shared__ unsigned short Ah[4096];   // 128x32 bf16
  __shared__ unsigned short Al[4096];
  __shared__ unsigned short Bt[4096];
  const int t = threadIdx.x;
  const int w = t >> 6, lane = t & 63;
  const int qL = lane & 15, quad = lane >> 4;
  const int bm = blockIdx.y * 128, bn = blockIdx.x * 128;
  const int wm = w >> 1, wn = w & 1;
  const int srow = lane >> 2;           // 0..15
  const int scol = (lane & 3) * 8;      // 0,8,16,24
  const unsigned short* ah_g = Xhi + (size_t)(bm + w * 16 + srow) * 1024 + scol;
  const unsigned short* al_g = Xlo + (size_t)(bm + w * 16 + srow) * 1024 + scol;
  const unsigned short* b_g  = Wb  + (size_t)(bn + w * 16 + srow) * 1024 + scol;
  unsigned short* ah_l = Ah + w * 512;  // wave-uniform LDS dest
  unsigned short* al_l = Al + w * 512;
  unsigned short* b_l  = Bt + w * 512;

  const f32x4 zz = {0.f, 0.f, 0.f, 0.f};
  f32x4 acc[4][4];
  #pragma unroll
  for (int i = 0; i < 4; ++i)
    #pragma unroll
    for (int j = 0; j < 4; ++j) acc[i][j] = zz;

  for (int k0 = 0; k0 < 1024; k0 += 32) {
    gld16(ah_g + k0,             ah_l);
    gld16(ah_g + 64 * 1024 + k0, ah_l + 2048);
    gld16(al_g + k0,             al_l);
    gld16(al_g + 64 * 1024 + k0, al_l + 2048);
    gld16(b_g  + k0,             b_l);
    gld16(b_g  + 64 * 1024 + k0, b_l  + 2048);
    __syncthreads();
    short8v bf[4], afh[4], afl[4];
    #pragma unroll
    for (int j = 0; j < 4; ++j)
      bf[j] = *(const short8v*)(Bt + (wn * 64 + j * 16 + qL) * 32 + quad * 8);
    #pragma unroll
    for (int i = 0; i < 4; ++i) {
      afh[i] = *(const short8v*)(Ah + (wm * 64 + i * 16 + qL) * 32 + quad * 8);
      afl[i] = *(const short8v*)(Al + (wm * 64 + i * 16 + qL) * 32 + quad * 8);
    }
    #pragma unroll
    for (int i = 0; i < 4; ++i)
      #pragma unroll
      for (int j = 0; j < 4; ++j) {
        acc[i][j] = __builtin_amdgcn_mfma_f32_16x16x32_bf16(afl[i], bf[j], acc[i][j], 0, 0, 0);
        acc[i][j] = __builtin_amdgcn_mfma_f32_16x16x32_bf16(afh[i], bf[j], acc[i][j], 0, 0, 0);
      }
    __syncthreads();
  }
  #pragma unroll
  for (int i = 0; i < 4; ++i) {
    const int row0 = bm + wm * 64 + i * 16 + quad * 4;
    #pragma unroll
    for (int j = 0; j < 4; ++j) {
      const int col = bn + wn * 64 + j * 16 + qL;
      #pragma unroll
      for (int r = 0; r < 4; ++r)
        C[(size_t)(row0 + r) * QKV_N + col] = acc[i][j][r];
    }
  }
}

// ---------------- rmsnorm + rope + q_gain -> bf16 [b][hh][s][32] ------------
__global__ void __launch_bounds__(256) k_normrope(const float* __restrict__ QKV,
    const float* __restrict__ cosT, const float* __restrict__ sinT,
    const float* __restrict__ q_gain,
    unsigned short* __restrict__ QB16, unsigned short* __restrict__ KB16) {
  int gid = blockIdx.x * 256 + threadIdx.x;
  int lane = gid & 63;
  int w = gid >> 6;            // wave id 0..131071
  int r = w >> 5;              // row 0..4095
  int u = w & 31;
  int isk = u >> 4, h = u & 15;
  float x = QKV[(size_t)r * 3072 + isk * 1024 + h * 64 + lane];
  float ss = x * x;
  #pragma unroll
  for (int off = 32; off >= 1; off >>= 1) ss += __shfl_xor(ss, off);
  float xn = x * rsqrtf(ss * (1.0f / 64.0f) + 1e-5f);
  int s = r & (SLEN - 1);
  int b = r >> 11;
  int j = lane & 31;
  float c = cosT[s * 32 + j], sn = sinT[s * 32 + j];
  float other = __shfl_xor(xn, 32);
  float o = (lane < 32) ? fmaf(xn, c, other * sn) : fmaf(xn, c, -other * sn);
  int hh = h + 16 * (lane >> 5);
  int dd = lane & 31;
  size_t addr = (((size_t)(b * 32 + hh) * SLEN) + s) * 32 + dd;
  if (!isk) {
    const float FOLD = 0.17677669529663687f * 1.4426950408889634f;
    QB16[addr] = f2bf(o * q_gain[h] * FOLD);
  } else {
    KB16[addr] = f2bf(o);
  }
}

// ---------------- V transpose -> bf16 VT16 [b][hh][d=32][s=2048] ------------
__global__ void __launch_bounds__(256) k_vtrans(const float* __restrict__ QKV,
                                                unsigned short* __restrict__ VT16) {
  __shared__ short Vt[64][34];
  const int s0 = blockIdx.x * 64, hh = blockIdx.y, b = blockIdx.z;
  const int vcb = 2048 + (hh & 15) * 64 + (hh >> 4) * 32;
  const int t = threadIdx.x;
  {
    int row = t >> 2, dpart = (t & 3) * 8;
    const float* p = QKV + (size_t)(b * SLEN + s0 + row) * 3072 + vcb + dpart;
    float4 a = *(const float4*)p;
    float4 bq = *(const float4*)(p + 4);
    Vt[row][dpart + 0] = (short)f2bf(a.x);  Vt[row][dpart + 1] = (short)f2bf(a.y);
    Vt[row][dpart + 2] = (short)f2bf(a.z);  Vt[row][dpart + 3] = (short)f2bf(a.w);
    Vt[row][dpart + 4] = (short)f2bf(bq.x); Vt[row][dpart + 5] = (short)f2bf(bq.y);
    Vt[row][dpart + 6] = (short)f2bf(bq.z); Vt[row][dpart + 7] = (short)f2bf(bq.w);
  }
  __syncthreads();
  {
    int d = t >> 3, spart = (t & 7) * 8;
    short8v v;
    #pragma unroll
    for (int i = 0; i < 8; ++i) v[i] = Vt[spart + i][d];
    *(short8v*)(VT16 + (((size_t)(b * 32 + hh) * 32) + d) * SLEN + s0 + spart) = v;
  }
}

// ---------------- MFMA flash attention (bf16, 16x16x32) ---------------------
__global__ void __launch_bounds__(256) k_attn(
    const unsigned short* __restrict__ QB16,
    const unsigned short* __restrict__ KB16,
    const unsigned short* __restrict__ VT16,
    float* __restrict__ OH) {
  __shared__ short Plds[4][16 * 32];     // per-wave 1 KB
  const int fid = blockIdx.x;            // 2048 blocks
  const int combo = fid & 63;
  const int p = fid >> 6;                // 0..31
  const int b = combo >> 5, hh = combo & 31;
  const int t = threadIdx.x;
  const int w = t >> 6, lane = t & 63;
  const int qL = lane & 15, quad = lane >> 4;
  int qt;                                 // balanced: chunk counts sum = 130
  if (w == 0) qt = p; else if (w == 1) qt = 63 - p;
  else if (w == 2) qt = 64 + p; else qt = 127 - p;
  const int q0 = qt * 16;
  const int qg = q0 + qL;

  const unsigned short* QB = QB16 + (size_t)(b * 32 + hh) * SLEN * 32;
  const unsigned short* KB = KB16 + (size_t)(b * 32 + hh) * SLEN * 32;
  const unsigned short* VT = VT16 + (size_t)(b * 32 + hh) * 32 * SLEN;

  const short8v qf = *(const short8v*)(QB + ((size_t)(q0 + qL) << 5) + (quad << 3));
  f32x4 acc0 = {0.f, 0.f, 0.f, 0.f};
  f32x4 acc1 = {0.f, 0.f, 0.f, 0.f};
  const f32x4 zz = {0.f, 0.f, 0.f, 0.f};
  float l = 0.f;
  short* Pw = &Plds[w][0];
  const int pws = (qL << 5) + (quad << 2);   // short4 store offset (tile0)
  const int pwr = (qL << 5) + (quad << 3);   // short8 read offset

  const int nch = (qt >> 1) + 1;
  for (int c = 0; c < nch; ++c) {
    const int k0 = c * 32;
    const unsigned short* kp = KB + ((size_t)(k0 + qL) << 5) + (quad << 3);
    short8v kf0 = *(const short8v*)kp;
    short8v kf1 = *(const short8v*)(kp + (16 << 5));
    const unsigned short* vp = VT + ((size_t)qL << 11) + k0 + (quad << 3);
    short8v vf0 = *(const short8v*)vp;
    short8v vf1 = *(const short8v*)(vp + (16 << 11));
    f32x4 st0 = __builtin_amdgcn_mfma_f32_16x16x32_bf16(kf0, qf, zz, 0, 0, 0);
    f32x4 st1 = __builtin_amdgcn_mfma_f32_16x16x32_bf16(kf1, qf, zz, 0, 0, 0);
    short4v pk0, pk1;
    if (c == nch - 1) {                      // masked tail (covers diagonal)
      const int kb0 = k0 + (quad << 2);
      #pragma unroll
      for (int r = 0; r < 4; ++r) {
        float pr = (kb0 + r <= qg) ? exp2f(st0[r]) : 0.f;
        l += pr; pk0[r] = (short)f2bf(pr);
      }
      #pragma unroll
      for (int r = 0; r < 4; ++r) {
        float pr = (kb0 + 16 + r <= qg) ? exp2f(st1[r]) : 0.f;
        l += pr; pk1[r] = (short)f2bf(pr);
      }
    } else {
      #pragma unroll
      for (int r = 0; r < 4; ++r) {
        float pr = exp2f(st0[r]); l += pr; pk0[r] = (short)f2bf(pr);
      }
      #pragma unroll
      for (int r = 0; r < 4; ++r) {
        float pr = exp2f(st1[r]); l += pr; pk1[r] = (short)f2bf(pr);
      }
    }
    *(short4v*)(Pw + pws)      = pk0;        // P^T[k][q] stored as Plds[q][k]
    *(short4v*)(Pw + pws + 16) = pk1;
    short8v pf = *(const short8v*)(Pw + pwr);
    acc0 = __builtin_amdgcn_mfma_f32_16x16x32_bf16(vf0, pf, acc0, 0, 0, 0);
    acc1 = __builtin_amdgcn_mfma_f32_16x16x32_bf16(vf1, pf, acc1, 0, 0, 0);
  }
  l += __shfl_xor(l, 16);
  l += __shfl_xor(l, 32);
  const float inv = 1.0f / l;
  float* ob = OH + (((size_t)(b * SLEN + q0 + qL) * 32) + hh) * 32 + (quad << 2);
  float4 o0 = {acc0[0] * inv, acc0[1] * inv, acc0[2] * inv, acc0[3] * inv};
  float4 o1 = {acc1[0] * inv, acc1[1] * inv, acc1[2] * inv, acc1[3] * inv};
  *(float4*)ob        = o0;
  *(float4*)(ob + 16) = o1;
}

// ---------------- differential combine: y = [y1 - lam*y2, y1 + lam*y2] -------
__global__ void __launch_bounds__(256) k_combine(const float* __restrict__ OH,
    const float* __restrict__ dl, float* __restrict__ Y) {
  int idx = blockIdx.x * 256 + threadIdx.x;   // 4096*16*32
  int d = idx & 31;
  int h = (idx >> 5) & 15;
  int r = idx >> 9;
  float y1 = OH[((size_t)r * 32 + h) * 32 + d];
  float y2 = OH[((size_t)r * 32 + h + 16) * 32 + d];
  float lam = dl[h];
  Y[(size_t)r * 1024 + h * 64 + d]      = y1 - lam * y2;
  Y[(size_t)r * 1024 + h * 64 + 32 + d] = y1 + lam * y2;
}

// ---------------- prototype projection -> A1T[f][o], A2T[f][o] ----------------
__global__ void __launch_bounds__(256) k_protproj(const float* __restrict__ PT,
    const float* __restrict__ features, const float* __restrict__ thp,
    const float* __restrict__ alp, const float* __restrict__ bep,
    float* __restrict__ A1T, float* __restrict__ A2T) {
  int o = blockIdx.x, t = threadIdx.x;
  int f = t >> 4, seg = t & 15;
  const float* pr = PT + (size_t)o * 1024 + seg * 64;
  const float* fr = features + (size_t)f * 1024 + seg * 64;
  float acc = 0.0f;
  #pragma unroll
  for (int i = 0; i < 64; i += 4) {
    float4 a = *(const float4*)(pr + i);
    float4 bq = *(const float4*)(fr + i);
    acc = fmaf(a.x, bq.x, acc); acc = fmaf(a.y, bq.y, acc);
    acc = fmaf(a.z, bq.z, acc); acc = fmaf(a.w, bq.w, acc);
  }
  acc += __shfl_xor(acc, 1); acc += __shfl_xor(acc, 2);
  acc += __shfl_xor(acc, 4); acc += __shfl_xor(acc, 8);
  if (seg == 0) {
    float pf = acc;
    float ps = 1.0f / (1.0f + expf(-5.0f * pf));
    float pa = pf * ps;
    A1T[f * 1024 + o] = fabsf(*thp) * pa - fabsf(*alp) * (1.0f - ps);
    A2T[f * 1024 + o] = -fabsf(*bep) * pa;
  }
}

// ---------------- x features: x_a and (1-x_s) ----------------
__global__ void __launch_bounds__(256) k_xfeat(const float* __restrict__ Y,
    const float* __restrict__ features, float* __restrict__ XA, float* __restrict__ XS1) {
  int r = blockIdx.x, t = threadIdx.x;
  int f = t >> 4, seg = t & 15;
  const float* yr = Y + (size_t)r * 1024 + seg * 64;
  const float* fr = features + (size_t)f * 1024 + seg * 64;
  float acc = 0.0f;
  #pragma unroll
  for (int i = 0; i < 64; i += 4) {
    float4 a = *(const float4*)(yr + i);
    float4 bq = *(const float4*)(fr + i);
    acc = fmaf(a.x, bq.x, acc); acc = fmaf(a.y, bq.y, acc);
    acc = fmaf(a.z, bq.z, acc); acc = fmaf(a.w, bq.w, acc);
  }
  acc += __shfl_xor(acc, 1); acc += __shfl_xor(acc, 2);
  acc += __shfl_xor(acc, 4); acc += __shfl_xor(acc, 8);
  if (seg == 0) {
    float xf = acc;
    float xs = 1.0f / (1.0f + expf(-5.0f * xf));
    XA[r * 16 + f] = xf * xs;
    XS1[r * 16 + f] = 1.0f - xs;
  }
}

// ---------------- final: out = XA @ A1T + XS1 @ A2T ----------------
__global__ void __launch_bounds__(256) k_final(const float* __restrict__ XA,
    const float* __restrict__ XS1, const float* __restrict__ A1T,
    const float* __restrict__ A2T, float* __restrict__ out) {
  int r = blockIdx.x, t = threadIdx.x;
  float xa[16], x1[16];
  #pragma unroll
  for (int f4 = 0; f4 < 16; f4 += 4) {
    float4 a = *(const float4*)(XA + r * 16 + f4);
    float4 b = *(const float4*)(XS1 + r * 16 + f4);
    xa[f4] = a.x; xa[f4 + 1] = a.y; xa[f4 + 2] = a.z; xa[f4 + 3] = a.w;
    x1[f4] = b.x; x1[f4 + 1] = b.y; x1[f4 + 2] = b.z; x1[f4 + 3] = b.w;
  }
  float4 acc = {0.f, 0.f, 0.f, 0.f};
  #pragma unroll
  for (int f = 0; f < 16; ++f) {
    float4 a1 = *(const float4*)(A1T + f * 1024 + t * 4);
    float4 a2 = *(const float4*)(A2T + f * 1024 + t * 4);
    acc.x = fmaf(xa[f], a1.x, fmaf(x1[f], a2.x, acc.x));
    acc.y = fmaf(xa[f], a1.y, fmaf(x1[f], a2.y, acc.y));
    acc.z = fmaf(xa[f], a1.z, fmaf(x1[f], a2.z, acc.z));
    acc.w = fmaf(xa[f], a1.w, fmaf(x1[f], a2.w, acc.w));
  }
  *(float4*)(out + (size_t)r * 1024 + t * 4) = acc;
}

extern "C" void kernel_launch(void* const* d_in, const int* in_sizes, int n_in,
                              void* d_out, int out_size, void* d_ws, size_t ws_size,
                              hipStream_t stream) {
  const float* x      = (const float*)d_in[0];
  const float* w_qkv  = (const float*)d_in[1];
  const float* feats  = (const float*)d_in[2];
  const float* protos = (const float*)d_in[3];
  const float* theta  = (const float*)d_in[4];
  const float* alpha  = (const float*)d_in[5];
  const float* beta   = (const float*)d_in[6];
  const float* q_gain = (const float*)d_in[7];
  const float* dlam   = (const float*)d_in[8];
  float* out = (float*)d_out;
  float* ws  = (float*)d_ws;

  // workspace layout: 18,120,704 floats + 24,117,248 shorts = 120.7 MB
  float* QKV = ws;                    // 12,582,912
  float* Y   = QKV;                   // alias: QKV dead after normrope+vtrans
  float* OH  = QKV + 12582912;        // 4,194,304
  float* COS = OH  + 4194304;         // 65,536
  float* SIN = COS + 65536;           // 65,536
  float* PT  = SIN + 65536;           // 1,048,576
  float* A1T = PT  + 1048576;         // 16,384
  float* A2T = A1T + 16384;           // 16,384
  float* XA  = A2T + 16384;           // 65,536
  float* XS1 = XA  + 65536;           // 65,536
  unsigned short* QB16 = (unsigned short*)(XS1 + 65536);  // 4,194,304
  unsigned short* KB16 = QB16 + 4194304;                  // 4,194,304
  unsigned short* VT16 = KB16 + 4194304;                  // 4,194,304
  unsigned short* Wb   = VT16 + 4194304;                  // 3,145,728
  unsigned short* Xhi  = Wb   + 3145728;                  // 4,194,304
  unsigned short* Xlo  = Xhi  + 4194304;                  // 4,194,304

  k_rope_tab<<<256, 256, 0, stream>>>(COS, SIN);
  k_ternary_bf16<<<12288, 256, 0, stream>>>(w_qkv, Wb);
  k_ternary<<<4096, 256, 0, stream>>>(protos, PT);
  k_xsplit<<<4096, 256, 0, stream>>>(x, Xhi, Xlo);
  dim3 gg(QKV_N / 128, NROWS / 128);
  k_gemm_mfma<<<gg, 256, 0, stream>>>(Xhi, Xlo, Wb, QKV);
  k_normrope<<<32768, 256, 0, stream>>>(QKV, COS, SIN, q_gain, QB16, KB16);
  dim3 gv(SLEN / 64, 32, BATCH);
  k_vtrans<<<gv, 256, 0, stream>>>(QKV, VT16);
  k_attn<<<2048, 256, 0, stream>>>(QB16, KB16, VT16, OH);
  k_combine<<<8192, 256, 0, stream>>>(OH, dlam, Y);
  k_protproj<<<1024, 256, 0, stream>>>(PT, feats, theta, alpha, beta, A1T, A2T);
  k_xfeat<<<4096, 256, 0, stream>>>(Y, feats, XA, XS1);
  k_final<<<4096, 256, 0, stream>>>(XA, XS1, A1T, A2T, out);
}

// Round 6
// 341.652 us; speedup vs baseline: 2.8860x; 1.1044x over previous
//
#include <hip/hip_runtime.h>
#include <hip/hip_bf16.h>
#include <math.h>

// Problem constants
#define DIM   1024
#define NHEAD 16
#define SLEN  2048
#define BATCH 2
#define NROWS (BATCH*SLEN)   // 4096
#define QKV_N 3072

typedef __attribute__((ext_vector_type(8))) short short8v;
typedef __attribute__((ext_vector_type(4))) short short4v;
typedef __attribute__((ext_vector_type(4))) float f32x4;

// RNE float->bf16 bit tricks (valid for finite, non-overflowing inputs —
// identical result to __float2bfloat16 / jnp astype for our value ranges)
__device__ __forceinline__ unsigned short rne16(float f) {
  unsigned u = __float_as_uint(f);
  u += 0x7FFFu + ((u >> 16) & 1u);
  return (unsigned short)(u >> 16);
}
__device__ __forceinline__ float rnef(float f) {
  unsigned u = __float_as_uint(f);
  u += 0x7FFFu + ((u >> 16) & 1u);
  return __uint_as_float(u & 0xFFFF0000u);
}
// pack two floats as bf16 pair (RNE), low = a, high = b
__device__ __forceinline__ unsigned pk2(float a, float b) {
  unsigned ua = __float_as_uint(a), ub = __float_as_uint(b);
  ua += 0x7FFFu + ((ua >> 16) & 1u);
  ub += 0x7FFFu + ((ub >> 16) & 1u);
  return (ua >> 16) | (ub & 0xFFFF0000u);
}

// async global->LDS, 16 bytes per lane; LDS dest = wave-uniform base + lane*16
__device__ __forceinline__ void gld16(const unsigned short* g, unsigned short* l) {
  __builtin_amdgcn_global_load_lds(
      (const __attribute__((address_space(1))) unsigned int*)g,
      (__attribute__((address_space(3))) unsigned int*)l, 16, 0, 0);
}

// ---------------- rope tables (match numpy f32 semantics) ----------------
__global__ void __launch_bounds__(256) k_rope_tab(float* __restrict__ cosT,
                                                  float* __restrict__ sinT) {
  int idx = blockIdx.x * 256 + threadIdx.x;        // 2048*32 = 65536
  int s = idx >> 5, j = idx & 31;
  double inv  = 1.0 / pow(10000.0, (double)(2 * j) / 64.0);
  double ramp = ((double)(2 * j) / 64.0 - 0.25) / 0.75;
  ramp = ramp < 0.0 ? 0.0 : (ramp > 1.0 ? 1.0 : ramp);
  inv /= (ramp * 3.0 + 1.0);                       // yarn: 1/scale - 1 = 3
  float freq = (float)s * (float)inv;              // f32 product like reference
  cosT[idx] = (float)cos((double)freq);
  sinT[idx] = (float)sin((double)freq);
}

// ---------------- ternary quantization (bf16-faithful) ----------------
// one 64-lane wave per group of 64 consecutive elements; fp32 output
__global__ void __launch_bounds__(256) k_ternary(const float* __restrict__ in,
                                                 float* __restrict__ out) {
  int idx = blockIdx.x * 256 + threadIdx.x;
  float wb = rnef(in[idx]);
  float a = fabsf(wb);
  #pragma unroll
  for (int off = 32; off >= 1; off >>= 1) a += __shfl_xor(a, off);
  float scale = rnef(a * (1.0f / 64.0f));
  scale = fmaxf(scale, 1e-8f);
  float ratio = rnef(wb / scale);
  float q = rintf(ratio);
  q = fminf(1.0f, fmaxf(-1.0f, q));
  float deq = rnef(q * scale);
  float d = rnef(deq - wb);
  out[idx] = rnef(wb + d);
}

// same, bf16 output (value is exactly bf16-representable)
__global__ void __launch_bounds__(256) k_ternary_bf16(const float* __restrict__ in,
                                                      unsigned short* __restrict__ out) {
  int idx = blockIdx.x * 256 + threadIdx.x;
  float wb = rnef(in[idx]);
  float a = fabsf(wb);
  #pragma unroll
  for (int off = 32; off >= 1; off >>= 1) a += __shfl_xor(a, off);
  float scale = rnef(a * (1.0f / 64.0f));
  scale = fmaxf(scale, 1e-8f);
  float ratio = rnef(wb / scale);
  float q = rintf(ratio);
  q = fminf(1.0f, fmaxf(-1.0f, q));
  float deq = rnef(q * scale);
  float d = rnef(deq - wb);
  out[idx] = rne16(wb + d);
}

// ---------------- split x into hi/lo bf16 (fp32-faithful pair) ----------------
__global__ void __launch_bounds__(256) k_xsplit(const float* __restrict__ x,
    unsigned short* __restrict__ Xhi, unsigned short* __restrict__ Xlo) {
  int idx = blockIdx.x * 256 + threadIdx.x;      // 1,048,576 threads x 4 elems
  float4 v = *(const float4*)(x + (size_t)idx * 4);
  short4v hi, lo;
  float h0 = rnef(v.x); hi[0] = (short)rne16(v.x); lo[0] = (short)rne16(v.x - h0);
  float h1 = rnef(v.y); hi[1] = (short)rne16(v.y); lo[1] = (short)rne16(v.y - h1);
  float h2 = rnef(v.z); hi[2] = (short)rne16(v.z); lo[2] = (short)rne16(v.z - h2);
  float h3 = rnef(v.w); hi[3] = (short)rne16(v.w); lo[3] = (short)rne16(v.w - h3);
  *(short4v*)(Xhi + (size_t)idx * 4) = hi;
  *(short4v*)(Xlo + (size_t)idx * 4) = lo;
}

// ---------------- bf16 MFMA GEMM: C[M=4096][N=3072] = (Xhi+Xlo)·Wb^T --------
__global__ void __launch_bounds__(256) k_gemm_mfma(
    const unsigned short* __restrict__ Xhi, const unsigned short* __restrict__ Xlo,
    const unsigned short* __restrict__ Wb, float* __restrict__ C) {
  __shared__ unsigned short Ah[4096];   // 128x32 bf16
  __shared__ unsigned short Al[4096];
  __shared__ unsigned short Bt[4096];
  const int t = threadIdx.x;
  const int w = t >> 6, lane = t & 63;
  const int qL = lane & 15, quad = lane >> 4;
  const int bm = blockIdx.y * 128, bn = blockIdx.x * 128;
  const int wm = w >> 1, wn = w & 1;
  const int srow = lane >> 2;           // 0..15
  const int scol = (lane & 3) * 8;      // 0,8,16,24
  const unsigned short* ah_g = Xhi + (size_t)(bm + w * 16 + srow) * 1024 + scol;
  const unsigned short* al_g = Xlo + (size_t)(bm + w * 16 + srow) * 1024 + scol;
  const unsigned short* b_g  = Wb  + (size_t)(bn + w * 16 + srow) * 1024 + scol;
  unsigned short* ah_l = Ah + w * 512;  // wave-uniform LDS dest
  unsigned short* al_l = Al + w * 512;
  unsigned short* b_l  = Bt + w * 512;

  const f32x4 zz = {0.f, 0.f, 0.f, 0.f};
  f32x4 acc[4][4];
  #pragma unroll
  for (int i = 0; i < 4; ++i)
    #pragma unroll
    for (int j = 0; j < 4; ++j) acc[i][j] = zz;

  for (int k0 = 0; k0 < 1024; k0 += 32) {
    gld16(ah_g + k0,             ah_l);
    gld16(ah_g + 64 * 1024 + k0, ah_l + 2048);
    gld16(al_g + k0,             al_l);
    gld16(al_g + 64 * 1024 + k0, al_l + 2048);
    gld16(b_g  + k0,             b_l);
    gld16(b_g  + 64 * 1024 + k0, b_l  + 2048);
    __syncthreads();
    short8v bf[4], afh[4], afl[4];
    #pragma unroll
    for (int j = 0; j < 4; ++j)
      bf[j] = *(const short8v*)(Bt + (wn * 64 + j * 16 + qL) * 32 + quad * 8);
    #pragma unroll
    for (int i = 0; i < 4; ++i) {
      afh[i] = *(const short8v*)(Ah + (wm * 64 + i * 16 + qL) * 32 + quad * 8);
      afl[i] = *(const short8v*)(Al + (wm * 64 + i * 16 + qL) * 32 + quad * 8);
    }
    #pragma unroll
    for (int i = 0; i < 4; ++i)
      #pragma unroll
      for (int j = 0; j < 4; ++j) {
        acc[i][j] = __builtin_amdgcn_mfma_f32_16x16x32_bf16(afl[i], bf[j], acc[i][j], 0, 0, 0);
        acc[i][j] = __builtin_amdgcn_mfma_f32_16x16x32_bf16(afh[i], bf[j], acc[i][j], 0, 0, 0);
      }
    __syncthreads();
  }
  #pragma unroll
  for (int i = 0; i < 4; ++i) {
    const int row0 = bm + wm * 64 + i * 16 + quad * 4;
    #pragma unroll
    for (int j = 0; j < 4; ++j) {
      const int col = bn + wn * 64 + j * 16 + qL;
      #pragma unroll
      for (int r = 0; r < 4; ++r)
        C[(size_t)(row0 + r) * QKV_N + col] = acc[i][j][r];
    }
  }
}

// ---------------- rmsnorm + rope + q_gain -> bf16 [b][hh][s][32] ------------
__global__ void __launch_bounds__(256) k_normrope(const float* __restrict__ QKV,
    const float* __restrict__ cosT, const float* __restrict__ sinT,
    const float* __restrict__ q_gain,
    unsigned short* __restrict__ QB16, unsigned short* __restrict__ KB16) {
  int gid = blockIdx.x * 256 + threadIdx.x;
  int lane = gid & 63;
  int w = gid >> 6;            // wave id 0..131071
  int r = w >> 5;              // row 0..4095
  int u = w & 31;
  int isk = u >> 4, h = u & 15;
  float x = QKV[(size_t)r * 3072 + isk * 1024 + h * 64 + lane];
  float ss = x * x;
  #pragma unroll
  for (int off = 32; off >= 1; off >>= 1) ss += __shfl_xor(ss, off);
  float xn = x * rsqrtf(ss * (1.0f / 64.0f) + 1e-5f);
  int s = r & (SLEN - 1);
  int b = r >> 11;
  int j = lane & 31;
  float c = cosT[s * 32 + j], sn = sinT[s * 32 + j];
  float other = __shfl_xor(xn, 32);
  float o = (lane < 32) ? fmaf(xn, c, other * sn) : fmaf(xn, c, -other * sn);
  int hh = h + 16 * (lane >> 5);
  int dd = lane & 31;
  size_t addr = (((size_t)(b * 32 + hh) * SLEN) + s) * 32 + dd;
  if (!isk) {
    const float FOLD = 0.17677669529663687f * 1.4426950408889634f;
    QB16[addr] = rne16(o * q_gain[h] * FOLD);
  } else {
    KB16[addr] = rne16(o);
  }
}

// ---------------- V transpose -> bf16 VT16 [b][hh][d=32][s=2048] ------------
__global__ void __launch_bounds__(256) k_vtrans(const float* __restrict__ QKV,
                                                unsigned short* __restrict__ VT16) {
  __shared__ short Vt[64][34];
  const int s0 = blockIdx.x * 64, hh = blockIdx.y, b = blockIdx.z;
  const int vcb = 2048 + (hh & 15) * 64 + (hh >> 4) * 32;
  const int t = threadIdx.x;
  {
    int row = t >> 2, dpart = (t & 3) * 8;
    const float* p = QKV + (size_t)(b * SLEN + s0 + row) * 3072 + vcb + dpart;
    float4 a = *(const float4*)p;
    float4 bq = *(const float4*)(p + 4);
    Vt[row][dpart + 0] = (short)rne16(a.x);  Vt[row][dpart + 1] = (short)rne16(a.y);
    Vt[row][dpart + 2] = (short)rne16(a.z);  Vt[row][dpart + 3] = (short)rne16(a.w);
    Vt[row][dpart + 4] = (short)rne16(bq.x); Vt[row][dpart + 5] = (short)rne16(bq.y);
    Vt[row][dpart + 6] = (short)rne16(bq.z); Vt[row][dpart + 7] = (short)rne16(bq.w);
  }
  __syncthreads();
  {
    int d = t >> 3, spart = (t & 7) * 8;
    short8v v;
    #pragma unroll
    for (int i = 0; i < 8; ++i) v[i] = Vt[spart + i][d];
    *(short8v*)(VT16 + (((size_t)(b * 32 + hh) * 32) + d) * SLEN + s0 + spart) = v;
  }
}

// ---------------- MFMA flash attention (bf16, 16x16x32), 2 q-tiles/wave -----
// Wave owns 32 q-rows (2 16-row tiles sharing K/V frags -> 8 MFMAs/chunk ILP).
// No barriers: per-wave private LDS region for the P C-layout->B-layout
// transform, row stride 40 shorts (80 B) to spread banks (~2-way, free).
// Fixed softmax shift m=0 (scores bounded by rmsnorm); manual RNE packs.
// Block p waves -> qb {p, 31-p, 32+p, 63-p}: exactly 130 chunks per block;
// 1024 blocks = 4096 waves = one full generation at 4 waves/SIMD.
__global__ void __launch_bounds__(256, 4) k_attn(
    const unsigned short* __restrict__ QB16,
    const unsigned short* __restrict__ KB16,
    const unsigned short* __restrict__ VT16,
    float* __restrict__ OH) {
  __shared__ short Plds[4][2][16 * 40];   // 10,240 B
  const int fid = blockIdx.x;             // 1024 blocks
  const int combo = fid & 63;             // XCD locality on (b,hh)
  const int p = fid >> 6;                 // 0..15
  const int b = combo >> 5, hh = combo & 31;
  const int t = threadIdx.x;
  const int w = t >> 6, lane = t & 63;
  const int qL = lane & 15, quad = lane >> 4;
  const int qb = (w == 0) ? p : (w == 1) ? (31 - p) : (w == 2) ? (32 + p) : (63 - p);
  const int q0 = qb * 32;

  const unsigned short* QB = QB16 + (size_t)(b * 32 + hh) * SLEN * 32;
  const unsigned short* KB = KB16 + (size_t)(b * 32 + hh) * SLEN * 32;
  const unsigned short* VT = VT16 + (size_t)(b * 32 + hh) * 32 * SLEN;

  const short8v qf0 = *(const short8v*)(QB + (size_t)(q0 + qL) * 32 + quad * 8);
  const short8v qf1 = *(const short8v*)(QB + (size_t)(q0 + 16 + qL) * 32 + quad * 8);
  const f32x4 zz = {0.f, 0.f, 0.f, 0.f};
  f32x4 a00 = zz, a01 = zz, a10 = zz, a11 = zz;
  float l0 = 0.f, l1 = 0.f;

  short* Pw0 = &Plds[w][0][0];
  short* Pw1 = &Plds[w][1][0];
  uint2* w00 = (uint2*)(Pw0 + qL * 40 + quad * 4);        // st0: k=4q..4q+3
  uint2* w01 = (uint2*)(Pw0 + qL * 40 + 16 + quad * 4);   // st1: k=16+4q..
  uint2* w10 = (uint2*)(Pw1 + qL * 40 + quad * 4);
  uint2* w11 = (uint2*)(Pw1 + qL * 40 + 16 + quad * 4);
  const short* r0 = Pw0 + qL * 40 + quad * 8;
  const short* r1 = Pw1 + qL * 40 + quad * 8;

  const unsigned short* kp = KB + (size_t)qL * 32 + quad * 8;
  const unsigned short* vp = VT + (size_t)qL * 2048 + quad * 8;

  for (int c = 0; c < qb; ++c) {         // full (unmasked) chunks
    short8v kf0 = *(const short8v*)kp;
    short8v kf1 = *(const short8v*)(kp + 512);
    short8v vf0 = *(const short8v*)vp;
    short8v vf1 = *(const short8v*)(vp + 32768);
    kp += 1024; vp += 32;
    f32x4 s00 = __builtin_amdgcn_mfma_f32_16x16x32_bf16(kf0, qf0, zz, 0, 0, 0);
    f32x4 s01 = __builtin_amdgcn_mfma_f32_16x16x32_bf16(kf1, qf0, zz, 0, 0, 0);
    f32x4 s10 = __builtin_amdgcn_mfma_f32_16x16x32_bf16(kf0, qf1, zz, 0, 0, 0);
    f32x4 s11 = __builtin_amdgcn_mfma_f32_16x16x32_bf16(kf1, qf1, zz, 0, 0, 0);
    float p00[4], p01[4], p10[4], p11[4];
    #pragma unroll
    for (int r = 0; r < 4; ++r) {
      p00[r] = __builtin_amdgcn_exp2f(s00[r]);
      p01[r] = __builtin_amdgcn_exp2f(s01[r]);
      p10[r] = __builtin_amdgcn_exp2f(s10[r]);
      p11[r] = __builtin_amdgcn_exp2f(s11[r]);
    }
    l0 += (p00[0] + p00[1] + p00[2] + p00[3]) + (p01[0] + p01[1] + p01[2] + p01[3]);
    l1 += (p10[0] + p10[1] + p10[2] + p10[3]) + (p11[0] + p11[1] + p11[2] + p11[3]);
    *w00 = (uint2){pk2(p00[0], p00[1]), pk2(p00[2], p00[3])};
    *w01 = (uint2){pk2(p01[0], p01[1]), pk2(p01[2], p01[3])};
    *w10 = (uint2){pk2(p10[0], p10[1]), pk2(p10[2], p10[3])};
    *w11 = (uint2){pk2(p11[0], p11[1]), pk2(p11[2], p11[3])};
    short8v pf0 = *(const short8v*)r0;
    short8v pf1 = *(const short8v*)r1;
    a00 = __builtin_amdgcn_mfma_f32_16x16x32_bf16(vf0, pf0, a00, 0, 0, 0);
    a01 = __builtin_amdgcn_mfma_f32_16x16x32_bf16(vf1, pf0, a01, 0, 0, 0);
    a10 = __builtin_amdgcn_mfma_f32_16x16x32_bf16(vf0, pf1, a10, 0, 0, 0);
    a11 = __builtin_amdgcn_mfma_f32_16x16x32_bf16(vf1, pf1, a11, 0, 0, 0);
  }
  {                                       // tail chunk (diagonal masks)
    short8v kf0 = *(const short8v*)kp;
    short8v kf1 = *(const short8v*)(kp + 512);
    short8v vf0 = *(const short8v*)vp;
    short8v vf1 = *(const short8v*)(vp + 32768);
    f32x4 s00 = __builtin_amdgcn_mfma_f32_16x16x32_bf16(kf0, qf0, zz, 0, 0, 0);
    f32x4 s10 = __builtin_amdgcn_mfma_f32_16x16x32_bf16(kf0, qf1, zz, 0, 0, 0);
    f32x4 s11 = __builtin_amdgcn_mfma_f32_16x16x32_bf16(kf1, qf1, zz, 0, 0, 0);
    float p00[4], p10[4], p11[4];
    #pragma unroll
    for (int r = 0; r < 4; ++r) {
      bool v = (4 * quad + r) <= qL;      // same predicate for s00 and s11
      p00[r] = v ? __builtin_amdgcn_exp2f(s00[r]) : 0.f;
      p10[r] = __builtin_amdgcn_exp2f(s10[r]);   // always valid
      p11[r] = v ? __builtin_amdgcn_exp2f(s11[r]) : 0.f;
    }
    l0 += (p00[0] + p00[1] + p00[2] + p00[3]);
    l1 += (p10[0] + p10[1] + p10[2] + p10[3]) + (p11[0] + p11[1] + p11[2] + p11[3]);
    *w00 = (uint2){pk2(p00[0], p00[1]), pk2(p00[2], p00[3])};
    *w01 = (uint2){0u, 0u};               // tile0 high-k fully masked
    *w10 = (uint2){pk2(p10[0], p10[1]), pk2(p10[2], p10[3])};
    *w11 = (uint2){pk2(p11[0], p11[1]), pk2(p11[2], p11[3])};
    short8v pf0 = *(const short8v*)r0;
    short8v pf1 = *(const short8v*)r1;
    a00 = __builtin_amdgcn_mfma_f32_16x16x32_bf16(vf0, pf0, a00, 0, 0, 0);
    a01 = __builtin_amdgcn_mfma_f32_16x16x32_bf16(vf1, pf0, a01, 0, 0, 0);
    a10 = __builtin_amdgcn_mfma_f32_16x16x32_bf16(vf0, pf1, a10, 0, 0, 0);
    a11 = __builtin_amdgcn_mfma_f32_16x16x32_bf16(vf1, pf1, a11, 0, 0, 0);
  }
  l0 += __shfl_xor(l0, 16); l0 += __shfl_xor(l0, 32);
  l1 += __shfl_xor(l1, 16); l1 += __shfl_xor(l1, 32);
  const float inv0 = 1.0f / l0, inv1 = 1.0f / l1;
  float* ob0 = OH + (((size_t)(b * SLEN + q0 + qL) * 32) + hh) * 32 + (quad << 2);
  float* ob1 = OH + (((size_t)(b * SLEN + q0 + 16 + qL) * 32) + hh) * 32 + (quad << 2);
  *(float4*)ob0        = (float4){a00[0] * inv0, a00[1] * inv0, a00[2] * inv0, a00[3] * inv0};
  *(float4*)(ob0 + 16) = (float4){a01[0] * inv0, a01[1] * inv0, a01[2] * inv0, a01[3] * inv0};
  *(float4*)ob1        = (float4){a10[0] * inv1, a10[1] * inv1, a10[2] * inv1, a10[3] * inv1};
  *(float4*)(ob1 + 16) = (float4){a11[0] * inv1, a11[1] * inv1, a11[2] * inv1, a11[3] * inv1};
}

// ---------------- differential combine: y = [y1 - lam*y2, y1 + lam*y2] -------
__global__ void __launch_bounds__(256) k_combine(const float* __restrict__ OH,
    const float* __restrict__ dl, float* __restrict__ Y) {
  int idx = blockIdx.x * 256 + threadIdx.x;   // 4096*16*32
  int d = idx & 31;
  int h = (idx >> 5) & 15;
  int r = idx >> 9;
  float y1 = OH[((size_t)r * 32 + h) * 32 + d];
  float y2 = OH[((size_t)r * 32 + h + 16) * 32 + d];
  float lam = dl[h];
  Y[(size_t)r * 1024 + h * 64 + d]      = y1 - lam * y2;
  Y[(size_t)r * 1024 + h * 64 + 32 + d] = y1 + lam * y2;
}

// ---------------- prototype projection -> A1T[f][o], A2T[f][o] ----------------
__global__ void __launch_bounds__(256) k_protproj(const float* __restrict__ PT,
    const float* __restrict__ features, const float* __restrict__ thp,
    const float* __restrict__ alp, const float* __restrict__ bep,
    float* __restrict__ A1T, float* __restrict__ A2T) {
  int o = blockIdx.x, t = threadIdx.x;
  int f = t >> 4, seg = t & 15;
  const float* pr = PT + (size_t)o * 1024 + seg * 64;
  const float* fr = features + (size_t)f * 1024 + seg * 64;
  float acc = 0.0f;
  #pragma unroll
  for (int i = 0; i < 64; i += 4) {
    float4 a = *(const float4*)(pr + i);
    float4 bq = *(const float4*)(fr + i);
    acc = fmaf(a.x, bq.x, acc); acc = fmaf(a.y, bq.y, acc);
    acc = fmaf(a.z, bq.z, acc); acc = fmaf(a.w, bq.w, acc);
  }
  acc += __shfl_xor(acc, 1); acc += __shfl_xor(acc, 2);
  acc += __shfl_xor(acc, 4); acc += __shfl_xor(acc, 8);
  if (seg == 0) {
    float pf = acc;
    float ps = 1.0f / (1.0f + expf(-5.0f * pf));
    float pa = pf * ps;
    A1T[f * 1024 + o] = fabsf(*thp) * pa - fabsf(*alp) * (1.0f - ps);
    A2T[f * 1024 + o] = -fabsf(*bep) * pa;
  }
}

// ---------------- x features: x_a and (1-x_s) ----------------
__global__ void __launch_bounds__(256) k_xfeat(const float* __restrict__ Y,
    const float* __restrict__ features, float* __restrict__ XA, float* __restrict__ XS1) {
  int r = blockIdx.x, t = threadIdx.x;
  int f = t >> 4, seg = t & 15;
  const float* yr = Y + (size_t)r * 1024 + seg * 64;
  const float* fr = features + (size_t)f * 1024 + seg * 64;
  float acc = 0.0f;
  #pragma unroll
  for (int i = 0; i < 64; i += 4) {
    float4 a = *(const float4*)(yr + i);
    float4 bq = *(const float4*)(fr + i);
    acc = fmaf(a.x, bq.x, acc); acc = fmaf(a.y, bq.y, acc);
    acc = fmaf(a.z, bq.z, acc); acc = fmaf(a.w, bq.w, acc);
  }
  acc += __shfl_xor(acc, 1); acc += __shfl_xor(acc, 2);
  acc += __shfl_xor(acc, 4); acc += __shfl_xor(acc, 8);
  if (seg == 0) {
    float xf = acc;
    float xs = 1.0f / (1.0f + expf(-5.0f * xf));
    XA[r * 16 + f] = xf * xs;
    XS1[r * 16 + f] = 1.0f - xs;
  }
}

// ---------------- final: out = XA @ A1T + XS1 @ A2T ----------------
__global__ void __launch_bounds__(256) k_final(const float* __restrict__ XA,
    const float* __restrict__ XS1, const float* __restrict__ A1T,
    const float* __restrict__ A2T, float* __restrict__ out) {
  int r = blockIdx.x, t = threadIdx.x;
  float xa[16], x1[16];
  #pragma unroll
  for (int f4 = 0; f4 < 16; f4 += 4) {
    float4 a = *(const float4*)(XA + r * 16 + f4);
    float4 b = *(const float4*)(XS1 + r * 16 + f4);
    xa[f4] = a.x; xa[f4 + 1] = a.y; xa[f4 + 2] = a.z; xa[f4 + 3] = a.w;
    x1[f4] = b.x; x1[f4 + 1] = b.y; x1[f4 + 2] = b.z; x1[f4 + 3] = b.w;
  }
  float4 acc = {0.f, 0.f, 0.f, 0.f};
  #pragma unroll
  for (int f = 0; f < 16; ++f) {
    float4 a1 = *(const float4*)(A1T + f * 1024 + t * 4);
    float4 a2 = *(const float4*)(A2T + f * 1024 + t * 4);
    acc.x = fmaf(xa[f], a1.x, fmaf(x1[f], a2.x, acc.x));
    acc.y = fmaf(xa[f], a1.y, fmaf(x1[f], a2.y, acc.y));
    acc.z = fmaf(xa[f], a1.z, fmaf(x1[f], a2.z, acc.z));
    acc.w = fmaf(xa[f], a1.w, fmaf(x1[f], a2.w, acc.w));
  }
  *(float4*)(out + (size_t)r * 1024 + t * 4) = acc;
}

extern "C" void kernel_launch(void* const* d_in, const int* in_sizes, int n_in,
                              void* d_out, int out_size, void* d_ws, size_t ws_size,
                              hipStream_t stream) {
  const float* x      = (const float*)d_in[0];
  const float* w_qkv  = (const float*)d_in[1];
  const float* feats  = (const float*)d_in[2];
  const float* protos = (const float*)d_in[3];
  const float* theta  = (const float*)d_in[4];
  const float* alpha  = (const float*)d_in[5];
  const float* beta   = (const float*)d_in[6];
  const float* q_gain = (const float*)d_in[7];
  const float* dlam   = (const float*)d_in[8];
  float* out = (float*)d_out;
  float* ws  = (float*)d_ws;

  // workspace layout: 18,120,704 floats + 24,117,248 shorts = 120.7 MB
  float* QKV = ws;                    // 12,582,912
  float* Y   = QKV;                   // alias: QKV dead after normrope+vtrans
  float* OH  = QKV + 12582912;        // 4,194,304
  float* COS = OH  + 4194304;         // 65,536
  float* SIN = COS + 65536;           // 65,536
  float* PT  = SIN + 65536;           // 1,048,576
  float* A1T = PT  + 1048576;         // 16,384
  float* A2T = A1T + 16384;           // 16,384
  float* XA  = A2T + 16384;           // 65,536
  float* XS1 = XA  + 65536;           // 65,536
  unsigned short* QB16 = (unsigned short*)(XS1 + 65536);  // 4,194,304
  unsigned short* KB16 = QB16 + 4194304;                  // 4,194,304
  unsigned short* VT16 = KB16 + 4194304;                  // 4,194,304
  unsigned short* Wb   = VT16 + 4194304;                  // 3,145,728
  unsigned short* Xhi  = Wb   + 3145728;                  // 4,194,304
  unsigned short* Xlo  = Xhi  + 4194304;                  // 4,194,304

  k_rope_tab<<<256, 256, 0, stream>>>(COS, SIN);
  k_ternary_bf16<<<12288, 256, 0, stream>>>(w_qkv, Wb);
  k_ternary<<<4096, 256, 0, stream>>>(protos, PT);
  k_xsplit<<<4096, 256, 0, stream>>>(x, Xhi, Xlo);
  dim3 gg(QKV_N / 128, NROWS / 128);
  k_gemm_mfma<<<gg, 256, 0, stream>>>(Xhi, Xlo, Wb, QKV);
  k_normrope<<<32768, 256, 0, stream>>>(QKV, COS, SIN, q_gain, QB16, KB16);
  dim3 gv(SLEN / 64, 32, BATCH);
  k_vtrans<<<gv, 256, 0, stream>>>(QKV, VT16);
  k_attn<<<1024, 256, 0, stream>>>(QB16, KB16, VT16, OH);
  k_combine<<<8192, 256, 0, stream>>>(OH, dlam, Y);
  k_protproj<<<1024, 256, 0, stream>>>(PT, feats, theta, alpha, beta, A1T, A2T);
  k_xfeat<<<4096, 256, 0, stream>>>(Y, feats, XA, XS1);
  k_final<<<4096, 256, 0, stream>>>(XA, XS1, A1T, A2T, out);
}

// Round 8
// 299.385 us; speedup vs baseline: 3.2935x; 1.1412x over previous
//
#include <hip/hip_runtime.h>
#include <hip/hip_bf16.h>
#include <math.h>

// Problem constants
#define DIM   1024
#define NHEAD 16
#define SLEN  2048
#define BATCH 2
#define NROWS (BATCH*SLEN)   // 4096
#define QKV_N 3072

typedef __attribute__((ext_vector_type(8))) short short8v;
typedef __attribute__((ext_vector_type(4))) short short4v;
typedef __attribute__((ext_vector_type(4))) float f32x4;

// RNE float->bf16 bit tricks (valid for finite, non-overflowing inputs —
// identical result to __float2bfloat16 / jnp astype for our value ranges)
__device__ __forceinline__ unsigned short rne16(float f) {
  unsigned u = __float_as_uint(f);
  u += 0x7FFFu + ((u >> 16) & 1u);
  return (unsigned short)(u >> 16);
}
__device__ __forceinline__ float rnef(float f) {
  unsigned u = __float_as_uint(f);
  u += 0x7FFFu + ((u >> 16) & 1u);
  return __uint_as_float(u & 0xFFFF0000u);
}
// pack two floats as bf16 pair (RNE), low = a, high = b
__device__ __forceinline__ unsigned pk2(float a, float b) {
  unsigned ua = __float_as_uint(a), ub = __float_as_uint(b);
  ua += 0x7FFFu + ((ua >> 16) & 1u);
  ub += 0x7FFFu + ((ub >> 16) & 1u);
  return (ua >> 16) | (ub & 0xFFFF0000u);
}

// async global->LDS, 16 bytes per lane; LDS dest = wave-uniform base + lane*16
__device__ __forceinline__ void gld16(const unsigned short* g, unsigned short* l) {
  __builtin_amdgcn_global_load_lds(
      (const __attribute__((address_space(1))) unsigned int*)g,
      (__attribute__((address_space(3))) unsigned int*)l, 16, 0, 0);
}

// ---------------- rope tables (match numpy f32 semantics) ----------------
__global__ void __launch_bounds__(256) k_rope_tab(float* __restrict__ cosT,
                                                  float* __restrict__ sinT) {
  int idx = blockIdx.x * 256 + threadIdx.x;        // 2048*32 = 65536
  int s = idx >> 5, j = idx & 31;
  double inv  = 1.0 / pow(10000.0, (double)(2 * j) / 64.0);
  double ramp = ((double)(2 * j) / 64.0 - 0.25) / 0.75;
  ramp = ramp < 0.0 ? 0.0 : (ramp > 1.0 ? 1.0 : ramp);
  inv /= (ramp * 3.0 + 1.0);                       // yarn: 1/scale - 1 = 3
  float freq = (float)s * (float)inv;              // f32 product like reference
  cosT[idx] = (float)cos((double)freq);
  sinT[idx] = (float)sin((double)freq);
}

// ---------------- ternary quantization (bf16-faithful) ----------------
// one 64-lane wave per group of 64 consecutive elements; fp32 output
__global__ void __launch_bounds__(256) k_ternary(const float* __restrict__ in,
                                                 float* __restrict__ out) {
  int idx = blockIdx.x * 256 + threadIdx.x;
  float wb = rnef(in[idx]);
  float a = fabsf(wb);
  #pragma unroll
  for (int off = 32; off >= 1; off >>= 1) a += __shfl_xor(a, off);
  float scale = rnef(a * (1.0f / 64.0f));
  scale = fmaxf(scale, 1e-8f);
  float ratio = rnef(wb / scale);
  float q = rintf(ratio);
  q = fminf(1.0f, fmaxf(-1.0f, q));
  float deq = rnef(q * scale);
  float d = rnef(deq - wb);
  out[idx] = rnef(wb + d);
}

// same, bf16 output (value is exactly bf16-representable)
__global__ void __launch_bounds__(256) k_ternary_bf16(const float* __restrict__ in,
                                                      unsigned short* __restrict__ out) {
  int idx = blockIdx.x * 256 + threadIdx.x;
  float wb = rnef(in[idx]);
  float a = fabsf(wb);
  #pragma unroll
  for (int off = 32; off >= 1; off >>= 1) a += __shfl_xor(a, off);
  float scale = rnef(a * (1.0f / 64.0f));
  scale = fmaxf(scale, 1e-8f);
  float ratio = rnef(wb / scale);
  float q = rintf(ratio);
  q = fminf(1.0f, fmaxf(-1.0f, q));
  float deq = rnef(q * scale);
  float d = rnef(deq - wb);
  out[idx] = rne16(wb + d);
}

// ---------------- split x into hi/lo bf16 (fp32-faithful pair) ----------------
__global__ void __launch_bounds__(256) k_xsplit(const float* __restrict__ x,
    unsigned short* __restrict__ Xhi, unsigned short* __restrict__ Xlo) {
  int idx = blockIdx.x * 256 + threadIdx.x;      // 1,048,576 threads x 4 elems
  float4 v = *(const float4*)(x + (size_t)idx * 4);
  short4v hi, lo;
  float h0 = rnef(v.x); hi[0] = (short)rne16(v.x); lo[0] = (short)rne16(v.x - h0);
  float h1 = rnef(v.y); hi[1] = (short)rne16(v.y); lo[1] = (short)rne16(v.y - h1);
  float h2 = rnef(v.z); hi[2] = (short)rne16(v.z); lo[2] = (short)rne16(v.z - h2);
  float h3 = rnef(v.w); hi[3] = (short)rne16(v.w); lo[3] = (short)rne16(v.w - h3);
  *(short4v*)(Xhi + (size_t)idx * 4) = hi;
  *(short4v*)(Xlo + (size_t)idx * 4) = lo;
}

// ---------------- bf16 MFMA GEMM: C[M=4096][N=3072] = (Xhi+Xlo)·Wb^T --------
__global__ void __launch_bounds__(256) k_gemm_mfma(
    const unsigned short* __restrict__ Xhi, const unsigned short* __restrict__ Xlo,
    const unsigned short* __restrict__ Wb, float* __restrict__ C) {
  __shared__ unsigned short Ah[4096];   // 128x32 bf16
  __shared__ unsigned short Al[4096];
  __shared__ unsigned short Bt[4096];
  const int t = threadIdx.x;
  const int w = t >> 6, lane = t & 63;
  const int qL = lane & 15, quad = lane >> 4;
  const int bm = blockIdx.y * 128, bn = blockIdx.x * 128;
  const int wm = w >> 1, wn = w & 1;
  const int srow = lane >> 2;           // 0..15
  const int scol = (lane & 3) * 8;      // 0,8,16,24
  const unsigned short* ah_g = Xhi + (size_t)(bm + w * 16 + srow) * 1024 + scol;
  const unsigned short* al_g = Xlo + (size_t)(bm + w * 16 + srow) * 1024 + scol;
  const unsigned short* b_g  = Wb  + (size_t)(bn + w * 16 + srow) * 1024 + scol;
  unsigned short* ah_l = Ah + w * 512;  // wave-uniform LDS dest
  unsigned short* al_l = Al + w * 512;
  unsigned short* b_l  = Bt + w * 512;

  const f32x4 zz = {0.f, 0.f, 0.f, 0.f};
  f32x4 acc[4][4];
  #pragma unroll
  for (int i = 0; i < 4; ++i)
    #pragma unroll
    for (int j = 0; j < 4; ++j) acc[i][j] = zz;

  for (int k0 = 0; k0 < 1024; k0 += 32) {
    gld16(ah_g + k0,             ah_l);
    gld16(ah_g + 64 * 1024 + k0, ah_l + 2048);
    gld16(al_g + k0,             al_l);
    gld16(al_g + 64 * 1024 + k0, al_l + 2048);
    gld16(b_g  + k0,             b_l);
    gld16(b_g  + 64 * 1024 + k0, b_l  + 2048);
    __syncthreads();
    short8v bf[4], afh[4], afl[4];
    #pragma unroll
    for (int j = 0; j < 4; ++j)
      bf[j] = *(const short8v*)(Bt + (wn * 64 + j * 16 + qL) * 32 + quad * 8);
    #pragma unroll
    for (int i = 0; i < 4; ++i) {
      afh[i] = *(const short8v*)(Ah + (wm * 64 + i * 16 + qL) * 32 + quad * 8);
      afl[i] = *(const short8v*)(Al + (wm * 64 + i * 16 + qL) * 32 + quad * 8);
    }
    #pragma unroll
    for (int i = 0; i < 4; ++i)
      #pragma unroll
      for (int j = 0; j < 4; ++j) {
        acc[i][j] = __builtin_amdgcn_mfma_f32_16x16x32_bf16(afl[i], bf[j], acc[i][j], 0, 0, 0);
        acc[i][j] = __builtin_amdgcn_mfma_f32_16x16x32_bf16(afh[i], bf[j], acc[i][j], 0, 0, 0);
      }
    __syncthreads();
  }
  #pragma unroll
  for (int i = 0; i < 4; ++i) {
    const int row0 = bm + wm * 64 + i * 16 + quad * 4;
    #pragma unroll
    for (int j = 0; j < 4; ++j) {
      const int col = bn + wn * 64 + j * 16 + qL;
      #pragma unroll
      for (int r = 0; r < 4; ++r)
        C[(size_t)(row0 + r) * QKV_N + col] = acc[i][j][r];
    }
  }
}

// ---------------- rmsnorm + rope + q_gain -> bf16 [b][hh][s][32] ------------
__global__ void __launch_bounds__(256) k_normrope(const float* __restrict__ QKV,
    const float* __restrict__ cosT, const float* __restrict__ sinT,
    const float* __restrict__ q_gain,
    unsigned short* __restrict__ QB16, unsigned short* __restrict__ KB16) {
  int gid = blockIdx.x * 256 + threadIdx.x;
  int lane = gid & 63;
  int w = gid >> 6;            // wave id 0..131071
  int r = w >> 5;              // row 0..4095
  int u = w & 31;
  int isk = u >> 4, h = u & 15;
  float x = QKV[(size_t)r * 3072 + isk * 1024 + h * 64 + lane];
  float ss = x * x;
  #pragma unroll
  for (int off = 32; off >= 1; off >>= 1) ss += __shfl_xor(ss, off);
  float xn = x * rsqrtf(ss * (1.0f / 64.0f) + 1e-5f);
  int s = r & (SLEN - 1);
  int b = r >> 11;
  int j = lane & 31;
  float c = cosT[s * 32 + j], sn = sinT[s * 32 + j];
  float other = __shfl_xor(xn, 32);
  float o = (lane < 32) ? fmaf(xn, c, other * sn) : fmaf(xn, c, -other * sn);
  int hh = h + 16 * (lane >> 5);
  int dd = lane & 31;
  size_t addr = (((size_t)(b * 32 + hh) * SLEN) + s) * 32 + dd;
  if (!isk) {
    const float FOLD = 0.17677669529663687f * 1.4426950408889634f;
    QB16[addr] = rne16(o * q_gain[h] * FOLD);
  } else {
    KB16[addr] = rne16(o);
  }
}

// ---------------- V transpose -> bf16 VT16 [b][hh][d=32][s=2048] ------------
__global__ void __launch_bounds__(256) k_vtrans(const float* __restrict__ QKV,
                                                unsigned short* __restrict__ VT16) {
  __shared__ short Vt[64][34];
  const int s0 = blockIdx.x * 64, hh = blockIdx.y, b = blockIdx.z;
  const int vcb = 2048 + (hh & 15) * 64 + (hh >> 4) * 32;
  const int t = threadIdx.x;
  {
    int row = t >> 2, dpart = (t & 3) * 8;
    const float* p = QKV + (size_t)(b * SLEN + s0 + row) * 3072 + vcb + dpart;
    float4 a = *(const float4*)p;
    float4 bq = *(const float4*)(p + 4);
    Vt[row][dpart + 0] = (short)rne16(a.x);  Vt[row][dpart + 1] = (short)rne16(a.y);
    Vt[row][dpart + 2] = (short)rne16(a.z);  Vt[row][dpart + 3] = (short)rne16(a.w);
    Vt[row][dpart + 4] = (short)rne16(bq.x); Vt[row][dpart + 5] = (short)rne16(bq.y);
    Vt[row][dpart + 6] = (short)rne16(bq.z); Vt[row][dpart + 7] = (short)rne16(bq.w);
  }
  __syncthreads();
  {
    int d = t >> 3, spart = (t & 7) * 8;
    short8v v;
    #pragma unroll
    for (int i = 0; i < 8; ++i) v[i] = Vt[spart + i][d];
    *(short8v*)(VT16 + (((size_t)(b * 32 + hh) * 32) + d) * SLEN + s0 + spart) = v;
  }
}

// ---------------- MFMA flash attention (bf16, 16x16x32), 2 q-tiles/wave -----
__global__ void __launch_bounds__(256, 4) k_attn(
    const unsigned short* __restrict__ QB16,
    const unsigned short* __restrict__ KB16,
    const unsigned short* __restrict__ VT16,
    float* __restrict__ OH) {
  __shared__ short Plds[4][2][16 * 40];   // 10,240 B
  const int fid = blockIdx.x;             // 1024 blocks
  const int combo = fid & 63;             // XCD locality on (b,hh)
  const int p = fid >> 6;                 // 0..15
  const int b = combo >> 5, hh = combo & 31;
  const int t = threadIdx.x;
  const int w = t >> 6, lane = t & 63;
  const int qL = lane & 15, quad = lane >> 4;
  const int qb = (w == 0) ? p : (w == 1) ? (31 - p) : (w == 2) ? (32 + p) : (63 - p);
  const int q0 = qb * 32;

  const unsigned short* QB = QB16 + (size_t)(b * 32 + hh) * SLEN * 32;
  const unsigned short* KB = KB16 + (size_t)(b * 32 + hh) * SLEN * 32;
  const unsigned short* VT = VT16 + (size_t)(b * 32 + hh) * 32 * SLEN;

  const short8v qf0 = *(const short8v*)(QB + (size_t)(q0 + qL) * 32 + quad * 8);
  const short8v qf1 = *(const short8v*)(QB + (size_t)(q0 + 16 + qL) * 32 + quad * 8);
  const f32x4 zz = {0.f, 0.f, 0.f, 0.f};
  f32x4 a00 = zz, a01 = zz, a10 = zz, a11 = zz;
  float l0 = 0.f, l1 = 0.f;

  short* Pw0 = &Plds[w][0][0];
  short* Pw1 = &Plds[w][1][0];
  uint2* w00 = (uint2*)(Pw0 + qL * 40 + quad * 4);        // st0: k=4q..4q+3
  uint2* w01 = (uint2*)(Pw0 + qL * 40 + 16 + quad * 4);   // st1: k=16+4q..
  uint2* w10 = (uint2*)(Pw1 + qL * 40 + quad * 4);
  uint2* w11 = (uint2*)(Pw1 + qL * 40 + 16 + quad * 4);
  const short* r0 = Pw0 + qL * 40 + quad * 8;
  const short* r1 = Pw1 + qL * 40 + quad * 8;

  const unsigned short* kp = KB + (size_t)qL * 32 + quad * 8;
  const unsigned short* vp = VT + (size_t)qL * 2048 + quad * 8;

  for (int c = 0; c < qb; ++c) {         // full (unmasked) chunks
    short8v kf0 = *(const short8v*)kp;
    short8v kf1 = *(const short8v*)(kp + 512);
    short8v vf0 = *(const short8v*)vp;
    short8v vf1 = *(const short8v*)(vp + 32768);
    kp += 1024; vp += 32;
    f32x4 s00 = __builtin_amdgcn_mfma_f32_16x16x32_bf16(kf0, qf0, zz, 0, 0, 0);
    f32x4 s01 = __builtin_amdgcn_mfma_f32_16x16x32_bf16(kf1, qf0, zz, 0, 0, 0);
    f32x4 s10 = __builtin_amdgcn_mfma_f32_16x16x32_bf16(kf0, qf1, zz, 0, 0, 0);
    f32x4 s11 = __builtin_amdgcn_mfma_f32_16x16x32_bf16(kf1, qf1, zz, 0, 0, 0);
    float p00[4], p01[4], p10[4], p11[4];
    #pragma unroll
    for (int r = 0; r < 4; ++r) {
      p00[r] = __builtin_amdgcn_exp2f(s00[r]);
      p01[r] = __builtin_amdgcn_exp2f(s01[r]);
      p10[r] = __builtin_amdgcn_exp2f(s10[r]);
      p11[r] = __builtin_amdgcn_exp2f(s11[r]);
    }
    l0 += (p00[0] + p00[1] + p00[2] + p00[3]) + (p01[0] + p01[1] + p01[2] + p01[3]);
    l1 += (p10[0] + p10[1] + p10[2] + p10[3]) + (p11[0] + p11[1] + p11[2] + p11[3]);
    *w00 = (uint2){pk2(p00[0], p00[1]), pk2(p00[2], p00[3])};
    *w01 = (uint2){pk2(p01[0], p01[1]), pk2(p01[2], p01[3])};
    *w10 = (uint2){pk2(p10[0], p10[1]), pk2(p10[2], p10[3])};
    *w11 = (uint2){pk2(p11[0], p11[1]), pk2(p11[2], p11[3])};
    short8v pf0 = *(const short8v*)r0;
    short8v pf1 = *(const short8v*)r1;
    a00 = __builtin_amdgcn_mfma_f32_16x16x32_bf16(vf0, pf0, a00, 0, 0, 0);
    a01 = __builtin_amdgcn_mfma_f32_16x16x32_bf16(vf1, pf0, a01, 0, 0, 0);
    a10 = __builtin_amdgcn_mfma_f32_16x16x32_bf16(vf0, pf1, a10, 0, 0, 0);
    a11 = __builtin_amdgcn_mfma_f32_16x16x32_bf16(vf1, pf1, a11, 0, 0, 0);
  }
  {                                       // tail chunk (diagonal masks)
    short8v kf0 = *(const short8v*)kp;
    short8v kf1 = *(const short8v*)(kp + 512);
    short8v vf0 = *(const short8v*)vp;
    short8v vf1 = *(const short8v*)(vp + 32768);
    f32x4 s00 = __builtin_amdgcn_mfma_f32_16x16x32_bf16(kf0, qf0, zz, 0, 0, 0);
    f32x4 s10 = __builtin_amdgcn_mfma_f32_16x16x32_bf16(kf0, qf1, zz, 0, 0, 0);
    f32x4 s11 = __builtin_amdgcn_mfma_f32_16x16x32_bf16(kf1, qf1, zz, 0, 0, 0);
    float p00[4], p10[4], p11[4];
    #pragma unroll
    for (int r = 0; r < 4; ++r) {
      bool v = (4 * quad + r) <= qL;      // same predicate for s00 and s11
      p00[r] = v ? __builtin_amdgcn_exp2f(s00[r]) : 0.f;
      p10[r] = __builtin_amdgcn_exp2f(s10[r]);   // always valid
      p11[r] = v ? __builtin_amdgcn_exp2f(s11[r]) : 0.f;
    }
    l0 += (p00[0] + p00[1] + p00[2] + p00[3]);
    l1 += (p10[0] + p10[1] + p10[2] + p10[3]) + (p11[0] + p11[1] + p11[2] + p11[3]);
    *w00 = (uint2){pk2(p00[0], p00[1]), pk2(p00[2], p00[3])};
    *w01 = (uint2){0u, 0u};               // tile0 high-k fully masked
    *w10 = (uint2){pk2(p10[0], p10[1]), pk2(p10[2], p10[3])};
    *w11 = (uint2){pk2(p11[0], p11[1]), pk2(p11[2], p11[3])};
    short8v pf0 = *(const short8v*)r0;
    short8v pf1 = *(const short8v*)r1;
    a00 = __builtin_amdgcn_mfma_f32_16x16x32_bf16(vf0, pf0, a00, 0, 0, 0);
    a01 = __builtin_amdgcn_mfma_f32_16x16x32_bf16(vf1, pf0, a01, 0, 0, 0);
    a10 = __builtin_amdgcn_mfma_f32_16x16x32_bf16(vf0, pf1, a10, 0, 0, 0);
    a11 = __builtin_amdgcn_mfma_f32_16x16x32_bf16(vf1, pf1, a11, 0, 0, 0);
  }
  l0 += __shfl_xor(l0, 16); l0 += __shfl_xor(l0, 32);
  l1 += __shfl_xor(l1, 16); l1 += __shfl_xor(l1, 32);
  const float inv0 = 1.0f / l0, inv1 = 1.0f / l1;
  float* ob0 = OH + (((size_t)(b * SLEN + q0 + qL) * 32) + hh) * 32 + (quad << 2);
  float* ob1 = OH + (((size_t)(b * SLEN + q0 + 16 + qL) * 32) + hh) * 32 + (quad << 2);
  *(float4*)ob0        = (float4){a00[0] * inv0, a00[1] * inv0, a00[2] * inv0, a00[3] * inv0};
  *(float4*)(ob0 + 16) = (float4){a01[0] * inv0, a01[1] * inv0, a01[2] * inv0, a01[3] * inv0};
  *(float4*)ob1        = (float4){a10[0] * inv1, a10[1] * inv1, a10[2] * inv1, a10[3] * inv1};
  *(float4*)(ob1 + 16) = (float4){a11[0] * inv1, a11[1] * inv1, a11[2] * inv1, a11[3] * inv1};
}

// ---------------- feature split: FS = Fa+Fb, FD = Fb-Fa --------------------
// F[f][h*64 + d] (d<32)=Fa applies to y1-lam*y2; F[f][h*64+32+d]=Fb to y1+lam*y2
// x_f = sum y1*(Fa+Fb) + lam*y2*(Fb-Fa); FS/FD layout [f][h*32+d]
__global__ void __launch_bounds__(256) k_fsplit(const float* __restrict__ F,
    float* __restrict__ FS, float* __restrict__ FD) {
  int idx = blockIdx.x * 256 + threadIdx.x;   // 8192
  int f = idx >> 9, hd = idx & 511;
  int h = hd >> 5, d = hd & 31;
  float a = F[f * 1024 + h * 64 + d];
  float b = F[f * 1024 + h * 64 + 32 + d];
  FS[idx] = a + b;
  FD[idx] = b - a;
}

// ---------------- fused combine + x-features (coalesced) --------------------
// Wave handles 2 rows; lane = dim-chunk (fully coalesced). Reads OH directly
// (no Y materialization). 16 dots via FS/FD factoring, butterfly reduce,
// lane-0 epilogue (sigmoid etc).
__device__ __forceinline__ float dot4(float4 a, float4 b) {
  return fmaf(a.x, b.x, fmaf(a.y, b.y, fmaf(a.z, b.z, a.w * b.w)));
}
__global__ void __launch_bounds__(256) k_cxf(const float* __restrict__ OH,
    const float* __restrict__ dl, const float* __restrict__ FS,
    const float* __restrict__ FD, float* __restrict__ XA, float* __restrict__ XS1) {
  const int t = threadIdx.x;
  const int w = t >> 6, lane = t & 63;
  const int r0 = blockIdx.x * 8 + w * 2;      // 512 blocks
  const float lam0 = dl[lane >> 3];           // h for i=0 float4
  const float lam1 = dl[8 + (lane >> 3)];     // h for i=1 float4
  const float* oh0 = OH + (size_t)r0 * 1024;
  float4 y1a0 = *(const float4*)(oh0 + lane * 4);
  float4 y1b0 = *(const float4*)(oh0 + 256 + lane * 4);
  float4 y2a0 = *(const float4*)(oh0 + 512 + lane * 4);
  float4 y2b0 = *(const float4*)(oh0 + 768 + lane * 4);
  float4 y1a1 = *(const float4*)(oh0 + 1024 + lane * 4);
  float4 y1b1 = *(const float4*)(oh0 + 1280 + lane * 4);
  float4 y2a1 = *(const float4*)(oh0 + 1536 + lane * 4);
  float4 y2b1 = *(const float4*)(oh0 + 1792 + lane * 4);
  y2a0.x *= lam0; y2a0.y *= lam0; y2a0.z *= lam0; y2a0.w *= lam0;
  y2b0.x *= lam1; y2b0.y *= lam1; y2b0.z *= lam1; y2b0.w *= lam1;
  y2a1.x *= lam0; y2a1.y *= lam0; y2a1.z *= lam0; y2a1.w *= lam0;
  y2b1.x *= lam1; y2b1.y *= lam1; y2b1.z *= lam1; y2b1.w *= lam1;
  float acc0[16], acc1[16];
  #pragma unroll
  for (int f = 0; f < 16; ++f) {
    float4 sa = *(const float4*)(FS + f * 512 + lane * 4);
    float4 sb = *(const float4*)(FS + f * 512 + 256 + lane * 4);
    float4 da = *(const float4*)(FD + f * 512 + lane * 4);
    float4 db = *(const float4*)(FD + f * 512 + 256 + lane * 4);
    acc0[f] = dot4(y1a0, sa) + dot4(y1b0, sb) + dot4(y2a0, da) + dot4(y2b0, db);
    acc1[f] = dot4(y1a1, sa) + dot4(y1b1, sb) + dot4(y2a1, da) + dot4(y2b1, db);
  }
  #pragma unroll
  for (int f = 0; f < 16; ++f) {
    #pragma unroll
    for (int off = 32; off >= 1; off >>= 1) {
      acc0[f] += __shfl_xor(acc0[f], off);
      acc1[f] += __shfl_xor(acc1[f], off);
    }
  }
  if (lane == 0) {
    #pragma unroll
    for (int f = 0; f < 16; ++f) {
      float xf = acc0[f];
      float xs = 1.0f / (1.0f + expf(-5.0f * xf));
      XA[(size_t)r0 * 16 + f] = xf * xs;
      XS1[(size_t)r0 * 16 + f] = 1.0f - xs;
      float xg = acc1[f];
      float xt = 1.0f / (1.0f + expf(-5.0f * xg));
      XA[(size_t)(r0 + 1) * 16 + f] = xg * xt;
      XS1[(size_t)(r0 + 1) * 16 + f] = 1.0f - xt;
    }
  }
}

// ---------------- prototype projection (coalesced) -> A1T[f][o], A2T[f][o] ---
// Wave per o-row; lane = dim-chunk; butterfly reduce; lane-0 epilogue.
__global__ void __launch_bounds__(256) k_protproj(const float* __restrict__ PT,
    const float* __restrict__ F, const float* __restrict__ thp,
    const float* __restrict__ alp, const float* __restrict__ bep,
    float* __restrict__ A1T, float* __restrict__ A2T) {
  const int t = threadIdx.x;
  const int w = t >> 6, lane = t & 63;
  const int o = blockIdx.x * 4 + w;           // 256 blocks
  const float* pr = PT + (size_t)o * 1024;
  float4 p0 = *(const float4*)(pr + lane * 4);
  float4 p1 = *(const float4*)(pr + 256 + lane * 4);
  float4 p2 = *(const float4*)(pr + 512 + lane * 4);
  float4 p3 = *(const float4*)(pr + 768 + lane * 4);
  float acc[16];
  #pragma unroll
  for (int f = 0; f < 16; ++f) {
    const float* fr = F + (size_t)f * 1024;
    float4 f0 = *(const float4*)(fr + lane * 4);
    float4 f1 = *(const float4*)(fr + 256 + lane * 4);
    float4 f2 = *(const float4*)(fr + 512 + lane * 4);
    float4 f3 = *(const float4*)(fr + 768 + lane * 4);
    acc[f] = dot4(p0, f0) + dot4(p1, f1) + dot4(p2, f2) + dot4(p3, f3);
  }
  #pragma unroll
  for (int f = 0; f < 16; ++f) {
    #pragma unroll
    for (int off = 32; off >= 1; off >>= 1) acc[f] += __shfl_xor(acc[f], off);
  }
  if (lane == 0) {
    float th = fabsf(*thp), al = fabsf(*alp), be = fabsf(*bep);
    #pragma unroll
    for (int f = 0; f < 16; ++f) {
      float pf = acc[f];
      float ps = 1.0f / (1.0f + expf(-5.0f * pf));
      float pa = pf * ps;
      A1T[f * 1024 + o] = th * pa - al * (1.0f - ps);
      A2T[f * 1024 + o] = -be * pa;
    }
  }
}

// ---------------- final: out = XA @ A1T + XS1 @ A2T ----------------
__global__ void __launch_bounds__(256) k_final(const float* __restrict__ XA,
    const float* __restrict__ XS1, const float* __restrict__ A1T,
    const float* __restrict__ A2T, float* __restrict__ out) {
  int r = blockIdx.x, t = threadIdx.x;
  float xa[16], x1[16];
  #pragma unroll
  for (int f4 = 0; f4 < 16; f4 += 4) {
    float4 a = *(const float4*)(XA + r * 16 + f4);
    float4 b = *(const float4*)(XS1 + r * 16 + f4);
    xa[f4] = a.x; xa[f4 + 1] = a.y; xa[f4 + 2] = a.z; xa[f4 + 3] = a.w;
    x1[f4] = b.x; x1[f4 + 1] = b.y; x1[f4 + 2] = b.z; x1[f4 + 3] = b.w;
  }
  float4 acc = {0.f, 0.f, 0.f, 0.f};
  #pragma unroll
  for (int f = 0; f < 16; ++f) {
    float4 a1 = *(const float4*)(A1T + f * 1024 + t * 4);
    float4 a2 = *(const float4*)(A2T + f * 1024 + t * 4);
    acc.x = fmaf(xa[f], a1.x, fmaf(x1[f], a2.x, acc.x));
    acc.y = fmaf(xa[f], a1.y, fmaf(x1[f], a2.y, acc.y));
    acc.z = fmaf(xa[f], a1.z, fmaf(x1[f], a2.z, acc.z));
    acc.w = fmaf(xa[f], a1.w, fmaf(x1[f], a2.w, acc.w));
  }
  *(float4*)(out + (size_t)r * 1024 + t * 4) = acc;
}

extern "C" void kernel_launch(void* const* d_in, const int* in_sizes, int n_in,
                              void* d_out, int out_size, void* d_ws, size_t ws_size,
                              hipStream_t stream) {
  const float* x      = (const float*)d_in[0];
  const float* w_qkv  = (const float*)d_in[1];
  const float* feats  = (const float*)d_in[2];
  const float* protos = (const float*)d_in[3];
  const float* theta  = (const float*)d_in[4];
  const float* alpha  = (const float*)d_in[5];
  const float* beta   = (const float*)d_in[6];
  const float* q_gain = (const float*)d_in[7];
  const float* dlam   = (const float*)d_in[8];
  float* out = (float*)d_out;
  float* ws  = (float*)d_ws;

  // workspace layout
  float* QKV = ws;                    // 12,582,912
  float* OH  = QKV + 12582912;        // 4,194,304
  float* COS = OH  + 4194304;         // 65,536
  float* SIN = COS + 65536;           // 65,536
  float* PT  = SIN + 65536;           // 1,048,576
  float* A1T = PT  + 1048576;         // 16,384
  float* A2T = A1T + 16384;           // 16,384
  float* XA  = A2T + 16384;           // 65,536
  float* XS1 = XA  + 65536;           // 65,536
  unsigned short* QB16 = (unsigned short*)(XS1 + 65536);  // 4,194,304
  unsigned short* KB16 = QB16 + 4194304;                  // 4,194,304
  unsigned short* VT16 = KB16 + 4194304;                  // 4,194,304
  unsigned short* Wb   = VT16 + 4194304;                  // 3,145,728
  unsigned short* Xhi  = Wb   + 3145728;                  // 4,194,304
  unsigned short* Xlo  = Xhi  + 4194304;                  // 4,194,304
  float* FS = (float*)(Xlo + 4194304);                    // 8,192
  float* FD = FS + 8192;                                  // 8,192

  k_rope_tab<<<256, 256, 0, stream>>>(COS, SIN);
  k_ternary_bf16<<<12288, 256, 0, stream>>>(w_qkv, Wb);
  k_ternary<<<4096, 256, 0, stream>>>(protos, PT);
  k_xsplit<<<4096, 256, 0, stream>>>(x, Xhi, Xlo);
  k_fsplit<<<32, 256, 0, stream>>>(feats, FS, FD);
  dim3 gg(QKV_N / 128, NROWS / 128);
  k_gemm_mfma<<<gg, 256, 0, stream>>>(Xhi, Xlo, Wb, QKV);
  k_normrope<<<32768, 256, 0, stream>>>(QKV, COS, SIN, q_gain, QB16, KB16);
  dim3 gv(SLEN / 64, 32, BATCH);
  k_vtrans<<<gv, 256, 0, stream>>>(QKV, VT16);
  k_attn<<<1024, 256, 0, stream>>>(QB16, KB16, VT16, OH);
  k_protproj<<<256, 256, 0, stream>>>(PT, feats, theta, alpha, beta, A1T, A2T);
  k_cxf<<<512, 256, 0, stream>>>(OH, dlam, FS, FD, XA, XS1);
  k_final<<<4096, 256, 0, stream>>>(XA, XS1, A1T, A2T, out);
}

// Round 11
// 271.919 us; speedup vs baseline: 3.6262x; 1.1010x over previous
//
#include <hip/hip_runtime.h>
#include <hip/hip_bf16.h>
#include <math.h>

// Problem constants
#define DIM   1024
#define NHEAD 16
#define SLEN  2048
#define BATCH 2
#define NROWS (BATCH*SLEN)   // 4096
#define QKV_N 3072

typedef __attribute__((ext_vector_type(8))) short short8v;
typedef __attribute__((ext_vector_type(4))) short short4v;
typedef __attribute__((ext_vector_type(4))) float f32x4;

// RNE float->bf16 bit tricks (valid for finite, non-overflowing inputs —
// identical result to __float2bfloat16 / jnp astype for our value ranges)
__device__ __forceinline__ unsigned short rne16(float f) {
  unsigned u = __float_as_uint(f);
  u += 0x7FFFu + ((u >> 16) & 1u);
  return (unsigned short)(u >> 16);
}
__device__ __forceinline__ float rnef(float f) {
  unsigned u = __float_as_uint(f);
  u += 0x7FFFu + ((u >> 16) & 1u);
  return __uint_as_float(u & 0xFFFF0000u);
}
// pack two floats as bf16 pair (RNE), low = a, high = b
__device__ __forceinline__ unsigned pk2(float a, float b) {
  unsigned ua = __float_as_uint(a), ub = __float_as_uint(b);
  ua += 0x7FFFu + ((ua >> 16) & 1u);
  ub += 0x7FFFu + ((ub >> 16) & 1u);
  return (ua >> 16) | (ub & 0xFFFF0000u);
}

// async global->LDS, 16 bytes per lane; LDS dest = wave-uniform base + lane*16
__device__ __forceinline__ void gld16(const unsigned short* g, unsigned short* l) {
  __builtin_amdgcn_global_load_lds(
      (const __attribute__((address_space(1))) unsigned int*)g,
      (__attribute__((address_space(3))) unsigned int*)l, 16, 0, 0);
}

// ================= k_prep: all independent input transforms =================
// blocks [0,12288)        ternary(w_qkv) -> bf16 Wb
// blocks [12288,16384)    ternary(protos) -> fp32 PT
// blocks [16384,20480)    xsplit (x -> Xhi,Xlo)
// blocks [20480,20736)    rope tables
// blocks [20736,20768)    feature split FS/FD
__global__ void __launch_bounds__(256) k_prep(
    const float* __restrict__ w_qkv, const float* __restrict__ protos,
    const float* __restrict__ x, const float* __restrict__ F,
    unsigned short* __restrict__ Wb, float* __restrict__ PT,
    unsigned short* __restrict__ Xhi, unsigned short* __restrict__ Xlo,
    float* __restrict__ cosT, float* __restrict__ sinT,
    float* __restrict__ FS, float* __restrict__ FD) {
  const int blk = blockIdx.x, tid = threadIdx.x;
  if (blk < 12288) {                       // ternary -> bf16
    int idx = blk * 256 + tid;
    float wb = rnef(w_qkv[idx]);
    float a = fabsf(wb);
    #pragma unroll
    for (int off = 32; off >= 1; off >>= 1) a += __shfl_xor(a, off);
    float scale = fmaxf(rnef(a * (1.0f / 64.0f)), 1e-8f);
    float q = fminf(1.0f, fmaxf(-1.0f, rintf(rnef(wb / scale))));
    float deq = rnef(q * scale);
    float d = rnef(deq - wb);
    Wb[idx] = rne16(wb + d);
  } else if (blk < 16384) {                // ternary -> fp32 (prototypes)
    int idx = (blk - 12288) * 256 + tid;
    float wb = rnef(protos[idx]);
    float a = fabsf(wb);
    #pragma unroll
    for (int off = 32; off >= 1; off >>= 1) a += __shfl_xor(a, off);
    float scale = fmaxf(rnef(a * (1.0f / 64.0f)), 1e-8f);
    float q = fminf(1.0f, fmaxf(-1.0f, rintf(rnef(wb / scale))));
    float deq = rnef(q * scale);
    float d = rnef(deq - wb);
    PT[idx] = rnef(wb + d);
  } else if (blk < 20480) {                // xsplit
    int idx = (blk - 16384) * 256 + tid;
    float4 v = *(const float4*)(x + (size_t)idx * 4);
    short4v hi, lo;
    float h0 = rnef(v.x); hi[0] = (short)rne16(v.x); lo[0] = (short)rne16(v.x - h0);
    float h1 = rnef(v.y); hi[1] = (short)rne16(v.y); lo[1] = (short)rne16(v.y - h1);
    float h2 = rnef(v.z); hi[2] = (short)rne16(v.z); lo[2] = (short)rne16(v.z - h2);
    float h3 = rnef(v.w); hi[3] = (short)rne16(v.w); lo[3] = (short)rne16(v.w - h3);
    *(short4v*)(Xhi + (size_t)idx * 4) = hi;
    *(short4v*)(Xlo + (size_t)idx * 4) = lo;
  } else if (blk < 20736) {                // rope tables
    int idx = (blk - 20480) * 256 + tid;   // 65536
    int s = idx >> 5, j = idx & 31;
    double inv  = 1.0 / pow(10000.0, (double)(2 * j) / 64.0);
    double ramp = ((double)(2 * j) / 64.0 - 0.25) / 0.75;
    ramp = ramp < 0.0 ? 0.0 : (ramp > 1.0 ? 1.0 : ramp);
    inv /= (ramp * 3.0 + 1.0);
    float freq = (float)s * (float)inv;
    cosT[idx] = (float)cos((double)freq);
    sinT[idx] = (float)sin((double)freq);
  } else {                                 // fsplit
    int idx = (blk - 20736) * 256 + tid;   // 8192
    int f = idx >> 9, hd = idx & 511;
    int h = hd >> 5, d = hd & 31;
    float a = F[f * 1024 + h * 64 + d];
    float b = F[f * 1024 + h * 64 + 32 + d];
    FS[idx] = a + b;
    FD[idx] = b - a;
  }
}

// ---------------- bf16 MFMA GEMM: C[M=4096][N=3072] = (Xhi+Xlo)·Wb^T --------
__global__ void __launch_bounds__(256) k_gemm_mfma(
    const unsigned short* __restrict__ Xhi, const unsigned short* __restrict__ Xlo,
    const unsigned short* __restrict__ Wb, float* __restrict__ C) {
  __shared__ unsigned short Ah[4096];   // 128x32 bf16
  __shared__ unsigned short Al[4096];
  __shared__ unsigned short Bt[4096];
  const int t = threadIdx.x;
  const int w = t >> 6, lane = t & 63;
  const int qL = lane & 15, quad = lane >> 4;
  const int bm = blockIdx.y * 128, bn = blockIdx.x * 128;
  const int wm = w >> 1, wn = w & 1;
  const int srow = lane >> 2;           // 0..15
  const int scol = (lane & 3) * 8;      // 0,8,16,24
  const unsigned short* ah_g = Xhi + (size_t)(bm + w * 16 + srow) * 1024 + scol;
  const unsigned short* al_g = Xlo + (size_t)(bm + w * 16 + srow) * 1024 + scol;
  const unsigned short* b_g  = Wb  + (size_t)(bn + w * 16 + srow) * 1024 + scol;
  unsigned short* ah_l = Ah + w * 512;  // wave-uniform LDS dest
  unsigned short* al_l = Al + w * 512;
  unsigned short* b_l  = Bt + w * 512;

  const f32x4 zz = {0.f, 0.f, 0.f, 0.f};
  f32x4 acc[4][4];
  #pragma unroll
  for (int i = 0; i < 4; ++i)
    #pragma unroll
    for (int j = 0; j < 4; ++j) acc[i][j] = zz;

  for (int k0 = 0; k0 < 1024; k0 += 32) {
    gld16(ah_g + k0,             ah_l);
    gld16(ah_g + 64 * 1024 + k0, ah_l + 2048);
    gld16(al_g + k0,             al_l);
    gld16(al_g + 64 * 1024 + k0, al_l + 2048);
    gld16(b_g  + k0,             b_l);
    gld16(b_g  + 64 * 1024 + k0, b_l  + 2048);
    __syncthreads();
    short8v bf[4], afh[4], afl[4];
    #pragma unroll
    for (int j = 0; j < 4; ++j)
      bf[j] = *(const short8v*)(Bt + (wn * 64 + j * 16 + qL) * 32 + quad * 8);
    #pragma unroll
    for (int i = 0; i < 4; ++i) {
      afh[i] = *(const short8v*)(Ah + (wm * 64 + i * 16 + qL) * 32 + quad * 8);
      afl[i] = *(const short8v*)(Al + (wm * 64 + i * 16 + qL) * 32 + quad * 8);
    }
    #pragma unroll
    for (int i = 0; i < 4; ++i)
      #pragma unroll
      for (int j = 0; j < 4; ++j) {
        acc[i][j] = __builtin_amdgcn_mfma_f32_16x16x32_bf16(afl[i], bf[j], acc[i][j], 0, 0, 0);
        acc[i][j] = __builtin_amdgcn_mfma_f32_16x16x32_bf16(afh[i], bf[j], acc[i][j], 0, 0, 0);
      }
    __syncthreads();
  }
  #pragma unroll
  for (int i = 0; i < 4; ++i) {
    const int row0 = bm + wm * 64 + i * 16 + quad * 4;
    #pragma unroll
    for (int j = 0; j < 4; ++j) {
      const int col = bn + wn * 64 + j * 16 + qL;
      #pragma unroll
      for (int r = 0; r < 4; ++r)
        C[(size_t)(row0 + r) * QKV_N + col] = acc[i][j][r];
    }
  }
}

// ================= k_mid: normrope + vtrans + protproj ======================
// blocks [0,32768)        rmsnorm+rope+gain -> QB16/KB16
// blocks [32768,34816)    V transpose -> VT16
// blocks [34816,35072)    prototype projection -> A1T/A2T
__device__ __forceinline__ float dot4(float4 a, float4 b) {
  return fmaf(a.x, b.x, fmaf(a.y, b.y, fmaf(a.z, b.z, a.w * b.w)));
}
__global__ void __launch_bounds__(256) k_mid(const float* __restrict__ QKV,
    const float* __restrict__ cosT, const float* __restrict__ sinT,
    const float* __restrict__ q_gain,
    unsigned short* __restrict__ QB16, unsigned short* __restrict__ KB16,
    unsigned short* __restrict__ VT16,
    const float* __restrict__ PT, const float* __restrict__ F,
    const float* __restrict__ thp, const float* __restrict__ alp,
    const float* __restrict__ bep,
    float* __restrict__ A1T, float* __restrict__ A2T) {
  __shared__ short Vt[64][34];
  const int blk = blockIdx.x, t = threadIdx.x;
  if (blk < 32768) {                       // normrope
    int gid = blk * 256 + t;
    int lane = gid & 63;
    int w = gid >> 6;
    int r = w >> 5;
    int u = w & 31;
    int isk = u >> 4, h = u & 15;
    float x = QKV[(size_t)r * 3072 + isk * 1024 + h * 64 + lane];
    float ss = x * x;
    #pragma unroll
    for (int off = 32; off >= 1; off >>= 1) ss += __shfl_xor(ss, off);
    float xn = x * rsqrtf(ss * (1.0f / 64.0f) + 1e-5f);
    int s = r & (SLEN - 1);
    int b = r >> 11;
    int j = lane & 31;
    float c = cosT[s * 32 + j], sn = sinT[s * 32 + j];
    float other = __shfl_xor(xn, 32);
    float o = (lane < 32) ? fmaf(xn, c, other * sn) : fmaf(xn, c, -other * sn);
    int hh = h + 16 * (lane >> 5);
    int dd = lane & 31;
    size_t addr = (((size_t)(b * 32 + hh) * SLEN) + s) * 32 + dd;
    if (!isk) {
      const float FOLD = 0.17677669529663687f * 1.4426950408889634f;
      QB16[addr] = rne16(o * q_gain[h] * FOLD);
    } else {
      KB16[addr] = rne16(o);
    }
  } else if (blk < 34816) {                // vtrans
    int i = blk - 32768;
    const int s0 = (i & 31) * 64, hh = (i >> 5) & 31, b = i >> 10;
    const int vcb = 2048 + (hh & 15) * 64 + (hh >> 4) * 32;
    {
      int row = t >> 2, dpart = (t & 3) * 8;
      const float* p = QKV + (size_t)(b * SLEN + s0 + row) * 3072 + vcb + dpart;
      float4 a = *(const float4*)p;
      float4 bq = *(const float4*)(p + 4);
      Vt[row][dpart + 0] = (short)rne16(a.x);  Vt[row][dpart + 1] = (short)rne16(a.y);
      Vt[row][dpart + 2] = (short)rne16(a.z);  Vt[row][dpart + 3] = (short)rne16(a.w);
      Vt[row][dpart + 4] = (short)rne16(bq.x); Vt[row][dpart + 5] = (short)rne16(bq.y);
      Vt[row][dpart + 6] = (short)rne16(bq.z); Vt[row][dpart + 7] = (short)rne16(bq.w);
    }
    __syncthreads();
    {
      int d = t >> 3, spart = (t & 7) * 8;
      short8v v;
      #pragma unroll
      for (int k = 0; k < 8; ++k) v[k] = Vt[spart + k][d];
      *(short8v*)(VT16 + (((size_t)(b * 32 + hh) * 32) + d) * SLEN + s0 + spart) = v;
    }
  } else {                                 // protproj (coalesced)
    const int w = t >> 6, lane = t & 63;
    const int o = (blk - 34816) * 4 + w;
    const float* pr = PT + (size_t)o * 1024;
    float4 p0 = *(const float4*)(pr + lane * 4);
    float4 p1 = *(const float4*)(pr + 256 + lane * 4);
    float4 p2 = *(const float4*)(pr + 512 + lane * 4);
    float4 p3 = *(const float4*)(pr + 768 + lane * 4);
    float acc[16];
    #pragma unroll
    for (int f = 0; f < 16; ++f) {
      const float* fr = F + (size_t)f * 1024;
      float4 f0 = *(const float4*)(fr + lane * 4);
      float4 f1 = *(const float4*)(fr + 256 + lane * 4);
      float4 f2 = *(const float4*)(fr + 512 + lane * 4);
      float4 f3 = *(const float4*)(fr + 768 + lane * 4);
      acc[f] = dot4(p0, f0) + dot4(p1, f1) + dot4(p2, f2) + dot4(p3, f3);
    }
    #pragma unroll
    for (int f = 0; f < 16; ++f) {
      #pragma unroll
      for (int off = 32; off >= 1; off >>= 1) acc[f] += __shfl_xor(acc[f], off);
    }
    if (lane == 0) {
      float th = fabsf(*thp), al = fabsf(*alp), be = fabsf(*bep);
      #pragma unroll
      for (int f = 0; f < 16; ++f) {
        float pf = acc[f];
        float ps = 1.0f / (1.0f + expf(-5.0f * pf));
        float pa = pf * ps;
        A1T[f * 1024 + o] = th * pa - al * (1.0f - ps);
        A2T[f * 1024 + o] = -be * pa;
      }
    }
  }
}

// ================ MFMA flash attention: 1 wave per block, LPT order =========
// 4096 blocks x 64 thr. Block fid: combo = fid&63 (XCD-local K/V), qb =
// 63 - fid>>6 (largest tiles dispatched first -> greedy LPT balancing).
// Wave owns 32 q-rows (2 16-row tiles), no barriers; per-wave LDS for the
// P C-layout -> B-layout transform (row stride 40 shorts, ~2-way banks).
__global__ void __launch_bounds__(64, 4) k_attn(
    const unsigned short* __restrict__ QB16,
    const unsigned short* __restrict__ KB16,
    const unsigned short* __restrict__ VT16,
    float* __restrict__ OH) {
  __shared__ short Plds[2][16 * 40];      // 2,560 B
  const int fid = blockIdx.x;             // 4096 blocks
  const int combo = fid & 63;
  const int qb = 63 - (fid >> 6);         // big first
  const int b = combo >> 5, hh = combo & 31;
  const int lane = threadIdx.x & 63;
  const int qL = lane & 15, quad = lane >> 4;
  const int q0 = qb * 32;

  const unsigned short* QB = QB16 + (size_t)(b * 32 + hh) * SLEN * 32;
  const unsigned short* KB = KB16 + (size_t)(b * 32 + hh) * SLEN * 32;
  const unsigned short* VT = VT16 + (size_t)(b * 32 + hh) * 32 * SLEN;

  const short8v qf0 = *(const short8v*)(QB + (size_t)(q0 + qL) * 32 + quad * 8);
  const short8v qf1 = *(const short8v*)(QB + (size_t)(q0 + 16 + qL) * 32 + quad * 8);
  const f32x4 zz = {0.f, 0.f, 0.f, 0.f};
  f32x4 a00 = zz, a01 = zz, a10 = zz, a11 = zz;
  float l0 = 0.f, l1 = 0.f;

  short* Pw0 = &Plds[0][0];
  short* Pw1 = &Plds[1][0];
  uint2* w00 = (uint2*)(Pw0 + qL * 40 + quad * 4);        // st0: k=4q..4q+3
  uint2* w01 = (uint2*)(Pw0 + qL * 40 + 16 + quad * 4);   // st1: k=16+4q..
  uint2* w10 = (uint2*)(Pw1 + qL * 40 + quad * 4);
  uint2* w11 = (uint2*)(Pw1 + qL * 40 + 16 + quad * 4);
  const short* r0 = Pw0 + qL * 40 + quad * 8;
  const short* r1 = Pw1 + qL * 40 + quad * 8;

  const unsigned short* kp = KB + (size_t)qL * 32 + quad * 8;
  const unsigned short* vp = VT + (size_t)qL * 2048 + quad * 8;

  for (int c = 0; c < qb; ++c) {         // full (unmasked) chunks
    short8v kf0 = *(const short8v*)kp;
    short8v kf1 = *(const short8v*)(kp + 512);
    short8v vf0 = *(const short8v*)vp;
    short8v vf1 = *(const short8v*)(vp + 32768);
    kp += 1024; vp += 32;
    f32x4 s00 = __builtin_amdgcn_mfma_f32_16x16x32_bf16(kf0, qf0, zz, 0, 0, 0);
    f32x4 s01 = __builtin_amdgcn_mfma_f32_16x16x32_bf16(kf1, qf0, zz, 0, 0, 0);
    f32x4 s10 = __builtin_amdgcn_mfma_f32_16x16x32_bf16(kf0, qf1, zz, 0, 0, 0);
    f32x4 s11 = __builtin_amdgcn_mfma_f32_16x16x32_bf16(kf1, qf1, zz, 0, 0, 0);
    float p00[4], p01[4], p10[4], p11[4];
    #pragma unroll
    for (int r = 0; r < 4; ++r) {
      p00[r] = __builtin_amdgcn_exp2f(s00[r]);
      p01[r] = __builtin_amdgcn_exp2f(s01[r]);
      p10[r] = __builtin_amdgcn_exp2f(s10[r]);
      p11[r] = __builtin_amdgcn_exp2f(s11[r]);
    }
    l0 += (p00[0] + p00[1] + p00[2] + p00[3]) + (p01[0] + p01[1] + p01[2] + p01[3]);
    l1 += (p10[0] + p10[1] + p10[2] + p10[3]) + (p11[0] + p11[1] + p11[2] + p11[3]);
    *w00 = (uint2){pk2(p00[0], p00[1]), pk2(p00[2], p00[3])};
    *w01 = (uint2){pk2(p01[0], p01[1]), pk2(p01[2], p01[3])};
    *w10 = (uint2){pk2(p10[0], p10[1]), pk2(p10[2], p10[3])};
    *w11 = (uint2){pk2(p11[0], p11[1]), pk2(p11[2], p11[3])};
    short8v pf0 = *(const short8v*)r0;
    short8v pf1 = *(const short8v*)r1;
    a00 = __builtin_amdgcn_mfma_f32_16x16x32_bf16(vf0, pf0, a00, 0, 0, 0);
    a01 = __builtin_amdgcn_mfma_f32_16x16x32_bf16(vf1, pf0, a01, 0, 0, 0);
    a10 = __builtin_amdgcn_mfma_f32_16x16x32_bf16(vf0, pf1, a10, 0, 0, 0);
    a11 = __builtin_amdgcn_mfma_f32_16x16x32_bf16(vf1, pf1, a11, 0, 0, 0);
  }
  {                                       // tail chunk (diagonal masks)
    short8v kf0 = *(const short8v*)kp;
    short8v kf1 = *(const short8v*)(kp + 512);
    short8v vf0 = *(const short8v*)vp;
    short8v vf1 = *(const short8v*)(vp + 32768);
    f32x4 s00 = __builtin_amdgcn_mfma_f32_16x16x32_bf16(kf0, qf0, zz, 0, 0, 0);
    f32x4 s10 = __builtin_amdgcn_mfma_f32_16x16x32_bf16(kf0, qf1, zz, 0, 0, 0);
    f32x4 s11 = __builtin_amdgcn_mfma_f32_16x16x32_bf16(kf1, qf1, zz, 0, 0, 0);
    float p00[4], p10[4], p11[4];
    #pragma unroll
    for (int r = 0; r < 4; ++r) {
      bool v = (4 * quad + r) <= qL;      // same predicate for s00 and s11
      p00[r] = v ? __builtin_amdgcn_exp2f(s00[r]) : 0.f;
      p10[r] = __builtin_amdgcn_exp2f(s10[r]);   // always valid
      p11[r] = v ? __builtin_amdgcn_exp2f(s11[r]) : 0.f;
    }
    l0 += (p00[0] + p00[1] + p00[2] + p00[3]);
    l1 += (p10[0] + p10[1] + p10[2] + p10[3]) + (p11[0] + p11[1] + p11[2] + p11[3]);
    *w00 = (uint2){pk2(p00[0], p00[1]), pk2(p00[2], p00[3])};
    *w01 = (uint2){0u, 0u};               // tile0 high-k fully masked
    *w10 = (uint2){pk2(p10[0], p10[1]), pk2(p10[2], p10[3])};
    *w11 = (uint2){pk2(p11[0], p11[1]), pk2(p11[2], p11[3])};
    short8v pf0 = *(const short8v*)r0;
    short8v pf1 = *(const short8v*)r1;
    a00 = __builtin_amdgcn_mfma_f32_16x16x32_bf16(vf0, pf0, a00, 0, 0, 0);
    a01 = __builtin_amdgcn_mfma_f32_16x16x32_bf16(vf1, pf0, a01, 0, 0, 0);
    a10 = __builtin_amdgcn_mfma_f32_16x16x32_bf16(vf0, pf1, a10, 0, 0, 0);
    a11 = __builtin_amdgcn_mfma_f32_16x16x32_bf16(vf1, pf1, a11, 0, 0, 0);
  }
  l0 += __shfl_xor(l0, 16); l0 += __shfl_xor(l0, 32);
  l1 += __shfl_xor(l1, 16); l1 += __shfl_xor(l1, 32);
  const float inv0 = 1.0f / l0, inv1 = 1.0f / l1;
  float* ob0 = OH + (((size_t)(b * SLEN + q0 + qL) * 32) + hh) * 32 + (quad << 2);
  float* ob1 = OH + (((size_t)(b * SLEN + q0 + 16 + qL) * 32) + hh) * 32 + (quad << 2);
  *(float4*)ob0        = (float4){a00[0] * inv0, a00[1] * inv0, a00[2] * inv0, a00[3] * inv0};
  *(float4*)(ob0 + 16) = (float4){a01[0] * inv0, a01[1] * inv0, a01[2] * inv0, a01[3] * inv0};
  *(float4*)ob1        = (float4){a10[0] * inv1, a10[1] * inv1, a10[2] * inv1, a10[3] * inv1};
  *(float4*)(ob1 + 16) = (float4){a11[0] * inv1, a11[1] * inv1, a11[2] * inv1, a11[3] * inv1};
}

// ================= k_tail: fused combine+xfeat + final ======================
// Block = 8 rows. Phase 1 (cxf): wave w reduces rows 2w,2w+1 -> XA/XS1 in LDS.
// Phase 2 (final): out[8][1024] = XA·A1T + XS1·A2T, A1T/A2T hoisted per-f.
__global__ void __launch_bounds__(256) k_tail(const float* __restrict__ OH,
    const float* __restrict__ dl, const float* __restrict__ FS,
    const float* __restrict__ FD, const float* __restrict__ A1T,
    const float* __restrict__ A2T, float* __restrict__ out) {
  __shared__ float XAs[8][16];
  __shared__ float XS1s[8][16];
  const int t = threadIdx.x;
  const int w = t >> 6, lane = t & 63;
  const int rbase = blockIdx.x * 8;           // 512 blocks
  {
    const float lam0 = dl[lane >> 3];
    const float lam1 = dl[8 + (lane >> 3)];
    const float* oh0 = OH + (size_t)(rbase + w * 2) * 1024;
    float4 y1a0 = *(const float4*)(oh0 + lane * 4);
    float4 y1b0 = *(const float4*)(oh0 + 256 + lane * 4);
    float4 y2a0 = *(const float4*)(oh0 + 512 + lane * 4);
    float4 y2b0 = *(const float4*)(oh0 + 768 + lane * 4);
    float4 y1a1 = *(const float4*)(oh0 + 1024 + lane * 4);
    float4 y1b1 = *(const float4*)(oh0 + 1280 + lane * 4);
    float4 y2a1 = *(const float4*)(oh0 + 1536 + lane * 4);
    float4 y2b1 = *(const float4*)(oh0 + 1792 + lane * 4);
    y2a0.x *= lam0; y2a0.y *= lam0; y2a0.z *= lam0; y2a0.w *= lam0;
    y2b0.x *= lam1; y2b0.y *= lam1; y2b0.z *= lam1; y2b0.w *= lam1;
    y2a1.x *= lam0; y2a1.y *= lam0; y2a1.z *= lam0; y2a1.w *= lam0;
    y2b1.x *= lam1; y2b1.y *= lam1; y2b1.z *= lam1; y2b1.w *= lam1;
    float acc0[16], acc1[16];
    #pragma unroll
    for (int f = 0; f < 16; ++f) {
      float4 sa = *(const float4*)(FS + f * 512 + lane * 4);
      float4 sb = *(const float4*)(FS + f * 512 + 256 + lane * 4);
      float4 da = *(const float4*)(FD + f * 512 + lane * 4);
      float4 db = *(const float4*)(FD + f * 512 + 256 + lane * 4);
      acc0[f] = dot4(y1a0, sa) + dot4(y1b0, sb) + dot4(y2a0, da) + dot4(y2b0, db);
      acc1[f] = dot4(y1a1, sa) + dot4(y1b1, sb) + dot4(y2a1, da) + dot4(y2b1, db);
    }
    #pragma unroll
    for (int f = 0; f < 16; ++f) {
      #pragma unroll
      for (int off = 32; off >= 1; off >>= 1) {
        acc0[f] += __shfl_xor(acc0[f], off);
        acc1[f] += __shfl_xor(acc1[f], off);
      }
    }
    if (lane == 0) {
      #pragma unroll
      for (int f = 0; f < 16; ++f) {
        float xf = acc0[f];
        float xs = 1.0f / (1.0f + expf(-5.0f * xf));
        XAs[w * 2][f] = xf * xs;
        XS1s[w * 2][f] = 1.0f - xs;
        float xg = acc1[f];
        float xt = 1.0f / (1.0f + expf(-5.0f * xg));
        XAs[w * 2 + 1][f] = xg * xt;
        XS1s[w * 2 + 1][f] = 1.0f - xt;
      }
    }
  }
  __syncthreads();
  {
    float4 acc[8];
    #pragma unroll
    for (int rr = 0; rr < 8; ++rr) acc[rr] = (float4){0.f, 0.f, 0.f, 0.f};
    #pragma unroll
    for (int f = 0; f < 16; ++f) {
      float4 a1 = *(const float4*)(A1T + f * 1024 + t * 4);
      float4 a2 = *(const float4*)(A2T + f * 1024 + t * 4);
      #pragma unroll
      for (int rr = 0; rr < 8; ++rr) {
        float xa = XAs[rr][f], x1 = XS1s[rr][f];
        acc[rr].x = fmaf(xa, a1.x, fmaf(x1, a2.x, acc[rr].x));
        acc[rr].y = fmaf(xa, a1.y, fmaf(x1, a2.y, acc[rr].y));
        acc[rr].z = fmaf(xa, a1.z, fmaf(x1, a2.z, acc[rr].z));
        acc[rr].w = fmaf(xa, a1.w, fmaf(x1, a2.w, acc[rr].w));
      }
    }
    #pragma unroll
    for (int rr = 0; rr < 8; ++rr)
      *(float4*)(out + (size_t)(rbase + rr) * 1024 + t * 4) = acc[rr];
  }
}

extern "C" void kernel_launch(void* const* d_in, const int* in_sizes, int n_in,
                              void* d_out, int out_size, void* d_ws, size_t ws_size,
                              hipStream_t stream) {
  const float* x      = (const float*)d_in[0];
  const float* w_qkv  = (const float*)d_in[1];
  const float* feats  = (const float*)d_in[2];
  const float* protos = (const float*)d_in[3];
  const float* theta  = (const float*)d_in[4];
  const float* alpha  = (const float*)d_in[5];
  const float* beta   = (const float*)d_in[6];
  const float* q_gain = (const float*)d_in[7];
  const float* dlam   = (const float*)d_in[8];
  float* out = (float*)d_out;
  float* ws  = (float*)d_ws;

  // workspace layout
  float* QKV = ws;                    // 12,582,912
  float* OH  = QKV + 12582912;        // 4,194,304
  float* COS = OH  + 4194304;         // 65,536
  float* SIN = COS + 65536;           // 65,536
  float* PT  = SIN + 65536;           // 1,048,576
  float* A1T = PT  + 1048576;         // 16,384
  float* A2T = A1T + 16384;           // 16,384
  float* XA  = A2T + 16384;           // 65,536 (unused, kept for layout)
  float* XS1 = XA  + 65536;           // 65,536 (unused)
  unsigned short* QB16 = (unsigned short*)(XS1 + 65536);  // 4,194,304
  unsigned short* KB16 = QB16 + 4194304;                  // 4,194,304
  unsigned short* VT16 = KB16 + 4194304;                  // 4,194,304
  unsigned short* Wb   = VT16 + 4194304;                  // 3,145,728
  unsigned short* Xhi  = Wb   + 3145728;                  // 4,194,304
  unsigned short* Xlo  = Xhi  + 4194304;                  // 4,194,304
  float* FS = (float*)(Xlo + 4194304);                    // 8,192
  float* FD = FS + 8192;                                  // 8,192

  k_prep<<<20768, 256, 0, stream>>>(w_qkv, protos, x, feats, Wb, PT,
                                    Xhi, Xlo, COS, SIN, FS, FD);
  dim3 gg(QKV_N / 128, NROWS / 128);
  k_gemm_mfma<<<gg, 256, 0, stream>>>(Xhi, Xlo, Wb, QKV);
  k_mid<<<35072, 256, 0, stream>>>(QKV, COS, SIN, q_gain, QB16, KB16, VT16,
                                   PT, feats, theta, alpha, beta, A1T, A2T);
  k_attn<<<4096, 64, 0, stream>>>(QB16, KB16, VT16, OH);
  k_tail<<<512, 256, 0, stream>>>(OH, dlam, FS, FD, A1T, A2T, out);
}